// Round 3
// baseline (936.934 us; speedup 1.0000x reference)
//
#include <hip/hip_runtime.h>
#include <hip/hip_bf16.h>
#include <math.h>

#define N_NODES  20000
#define E_EDGES  320000
#define E_TOT    (E_EDGES + N_NODES)
#define F_INF    256
#define HEADS    8
#define CDIM     64
#define HID      512
#define B_GRAPHS 64
#define NCLS     10
#define M_PAD    20096          // 157 * 128

typedef __attribute__((ext_vector_type(8))) short short8;
typedef __attribute__((ext_vector_type(4))) float f32x4;

__device__ inline unsigned short f2bf(float x) {
    unsigned u = __builtin_bit_cast(unsigned, x);
    u += 0x7fff + ((u >> 16) & 1);          // round-to-nearest-even
    return (unsigned short)(u >> 16);
}
__device__ inline float bf2f(unsigned short h) {
    unsigned u = ((unsigned)h) << 16;
    return __builtin_bit_cast(float, u);
}

#define GLOAD_LDS16(g, l) __builtin_amdgcn_global_load_lds(                     \
        (const __attribute__((address_space(1))) void*)(g),                     \
        (__attribute__((address_space(3))) void*)(l), 16, 0, 0)

// ---------------------------------------------------------------- utils
__global__ __launch_bounds__(256) void zero_ints(int* p, int n) {
    int i = blockIdx.x * 256 + threadIdx.x;
    if (i < n) p[i] = 0;
}

__global__ __launch_bounds__(256) void zero_pad_rows(unsigned short* hi, unsigned short* lo) {
    int i = blockIdx.x * 256 + threadIdx.x;
    const int tot = (M_PAD - N_NODES) * HID;
    if (i < tot) {
        hi[(size_t)N_NODES * HID + i] = 0;
        lo[(size_t)N_NODES * HID + i] = 0;
    }
}

// ---------------------------------------------------------------- fp32 -> bf16 hi/lo split (row-padded)
__global__ __launch_bounds__(256) void split_pad(const float* __restrict__ src,
                                                 unsigned short* __restrict__ hi,
                                                 unsigned short* __restrict__ lo,
                                                 int M, int K, long total) {
    long i = ((long)blockIdx.x * 256 + threadIdx.x) * 4;
    if (i >= total) return;
    int row = (int)(i / K);
    float4 v = make_float4(0.f, 0.f, 0.f, 0.f);
    if (row < M) v = *(const float4*)(src + i);
    ushort4 h, l;
    h.x = f2bf(v.x); l.x = f2bf(v.x - bf2f(h.x));
    h.y = f2bf(v.y); l.y = f2bf(v.y - bf2f(h.y));
    h.z = f2bf(v.z); l.z = f2bf(v.z - bf2f(h.z));
    h.w = f2bf(v.w); l.w = f2bf(v.w - bf2f(h.w));
    *(ushort4*)(hi + i) = h;
    *(ushort4*)(lo + i) = l;
}

// ---------------------------------------------------------------- B[K][512] -> Bt_hi/lo[512][K]
__global__ __launch_bounds__(256) void transpose_split_B(const float* __restrict__ B,
                                                         unsigned short* __restrict__ Bthi,
                                                         unsigned short* __restrict__ Btlo,
                                                         int K) {
    __shared__ float t[32][33];
    int n0 = blockIdx.x * 32, k0 = blockIdx.y * 32;
    int tx = threadIdx.x & 31, ty = threadIdx.x >> 5;     // 32 x 8
    for (int i = ty; i < 32; i += 8) t[i][tx] = B[(size_t)(k0 + i) * HID + n0 + tx];
    __syncthreads();
    for (int i = ty; i < 32; i += 8) {
        float v = t[tx][i];                                // = B[k0+tx][n0+i]
        unsigned short h = f2bf(v);
        unsigned short l = f2bf(v - bf2f(h));
        Bthi[(size_t)(n0 + i) * K + k0 + tx] = h;
        Btlo[(size_t)(n0 + i) * K + k0 + tx] = l;
    }
}

// ---------------------------------------------------------------- bf16x3 MFMA GEMM -> head-major xth[H][N][64]
__global__ __launch_bounds__(256) void gemm_mfma(const unsigned short* __restrict__ Ahi,
                                                 const unsigned short* __restrict__ Alo,
                                                 const unsigned short* __restrict__ Bhi,
                                                 const unsigned short* __restrict__ Blo,
                                                 float* __restrict__ xth,
                                                 int M, int K) {
    __shared__ short AsHi[4096], AsLo[4096], BsHi[4096], BsLo[4096]; // [128 rows][32 k] swizzled
    const int tid = threadIdx.x;
    const int w = tid >> 6, lane = tid & 63;
    const int wr = w >> 1, wc = w & 1;
    const int row0 = blockIdx.x * 128, col0 = blockIdx.y * 128;

    long offA[2], offB[2];
    int ldsU[2];
#pragma unroll
    for (int i = 0; i < 2; ++i) {
        int u = w * 128 + i * 64 + lane;
        int row = u >> 2;
        int kg = (u & 3) ^ (row & 3);
        offA[i] = ((long)(row0 + row) * K + kg * 8) * 2;   // bytes
        offB[i] = ((long)(col0 + row) * K + kg * 8) * 2;
        ldsU[i] = (w * 128 + i * 64) * 8;                  // short index of LDS base
    }

    const int r16 = lane & 15, kg = lane >> 4;
    int aOff[4], bOff[4];
#pragma unroll
    for (int i = 0; i < 4; ++i) {
        int row = wr * 64 + i * 16 + r16;
        aOff[i] = (row * 4 + (kg ^ (row & 3))) * 16;
        int col = wc * 64 + i * 16 + r16;
        bOff[i] = (col * 4 + (kg ^ (col & 3))) * 16;
    }

    const char* pAhi = (const char*)Ahi;
    const char* pAlo = (const char*)Alo;
    const char* pBhi = (const char*)Bhi;
    const char* pBlo = (const char*)Blo;

    f32x4 acc[4][4] = {};

    for (int kk = 0; kk < K; kk += 32) {
        long kb = (long)kk * 2;
        __syncthreads();
#pragma unroll
        for (int i = 0; i < 2; ++i) {
            GLOAD_LDS16(pAhi + offA[i] + kb, AsHi + ldsU[i]);
            GLOAD_LDS16(pAlo + offA[i] + kb, AsLo + ldsU[i]);
            GLOAD_LDS16(pBhi + offB[i] + kb, BsHi + ldsU[i]);
            GLOAD_LDS16(pBlo + offB[i] + kb, BsLo + ldsU[i]);
        }
        __syncthreads();

        short8 ah[4], al[4], bh[4], bl[4];
#pragma unroll
        for (int i = 0; i < 4; ++i) {
            ah[i] = *(const short8*)((const char*)AsHi + aOff[i]);
            al[i] = *(const short8*)((const char*)AsLo + aOff[i]);
            bh[i] = *(const short8*)((const char*)BsHi + bOff[i]);
            bl[i] = *(const short8*)((const char*)BsLo + bOff[i]);
        }
#pragma unroll
        for (int i = 0; i < 4; ++i)
#pragma unroll
            for (int j = 0; j < 4; ++j) {
                acc[i][j] = __builtin_amdgcn_mfma_f32_16x16x32_bf16(ah[i], bh[j], acc[i][j], 0, 0, 0);
                acc[i][j] = __builtin_amdgcn_mfma_f32_16x16x32_bf16(ah[i], bl[j], acc[i][j], 0, 0, 0);
                acc[i][j] = __builtin_amdgcn_mfma_f32_16x16x32_bf16(al[i], bh[j], acc[i][j], 0, 0, 0);
            }
    }

    // epilogue: C/D layout col=lane&15, row=(lane>>4)*4+r; write head-major
#pragma unroll
    for (int i = 0; i < 4; ++i) {
        int rbase = row0 + wr * 64 + i * 16 + (lane >> 4) * 4;
#pragma unroll
        for (int j = 0; j < 4; ++j) {
            int col = col0 + wc * 64 + j * 16 + r16;
            float* dst = xth + ((size_t)(col >> 6) * N_NODES) * CDIM + (col & 63);
#pragma unroll
            for (int r = 0; r < 4; ++r)
                if (rbase + r < M) dst[(size_t)(rbase + r) * CDIM] = acc[i][j][r];
        }
    }
}

// ---------------------------------------------------------------- al_s / al_d  (one wave per (n,h))
__global__ __launch_bounds__(256) void compute_al(const float* __restrict__ xth,
                                                  const float* __restrict__ a_src,
                                                  const float* __restrict__ a_dst,
                                                  float* __restrict__ al_s,
                                                  float* __restrict__ al_d) {
    int tid = threadIdx.x;
    int w = blockIdx.x * 4 + (tid >> 6);     // global wave id
    int lane = tid & 63;
    int n = w >> 3;
    int h = w & 7;
    float v = xth[((size_t)h * N_NODES + n) * CDIM + lane];
    float s = v * a_src[h * CDIM + lane];
    float d = v * a_dst[h * CDIM + lane];
#pragma unroll
    for (int off = 32; off; off >>= 1) {
        s += __shfl_xor(s, off);
        d += __shfl_xor(d, off);
    }
    if (lane == 0) {
        al_s[n * HEADS + h] = s;
        al_d[n * HEADS + h] = d;
    }
}

// ---------------------------------------------------------------- CSR build
__global__ __launch_bounds__(256) void count_edges(const int* __restrict__ ei,
                                                   int* __restrict__ counts) {
    int e = blockIdx.x * 256 + threadIdx.x;
    if (e < E_TOT) {
        int dst = (e < E_EDGES) ? ei[E_EDGES + e] : (e - E_EDGES);
        atomicAdd(&counts[dst], 1);
    }
}

__global__ __launch_bounds__(1024) void scan_counts(const int* __restrict__ counts,
                                                    int* __restrict__ offsets,
                                                    int* __restrict__ cursor) {
    __shared__ int sdata[1024];
    __shared__ int carry_s;
    int tid = threadIdx.x;
    if (tid == 0) { carry_s = 0; offsets[0] = 0; }
    __syncthreads();
    for (int base = 0; base < N_NODES; base += 1024) {
        int i = base + tid;
        int v = (i < N_NODES) ? counts[i] : 0;
        sdata[tid] = v;
        __syncthreads();
        for (int off = 1; off < 1024; off <<= 1) {
            int t = (tid >= off) ? sdata[tid - off] : 0;
            __syncthreads();
            sdata[tid] += t;
            __syncthreads();
        }
        int incl = sdata[tid] + carry_s;
        if (i < N_NODES) {
            offsets[i + 1] = incl;
            cursor[i] = incl - v;   // exclusive offset
        }
        __syncthreads();
        if (tid == 0) carry_s += sdata[1023];
        __syncthreads();
    }
}

__global__ __launch_bounds__(256) void scatter_edges(const int* __restrict__ ei,
                                                     int* __restrict__ cursor,
                                                     int* __restrict__ csr) {
    int e = blockIdx.x * 256 + threadIdx.x;
    if (e < E_TOT) {
        int dst = (e < E_EDGES) ? ei[E_EDGES + e] : (e - E_EDGES);
        int pos = atomicAdd(&cursor[dst], 1);
        csr[pos] = e;
    }
}

// ---------------------------------------------------------------- GAT aggregation: one wave per (node, head)
// grid = (N/4, HEADS); head varies slowest -> concurrent blocks share one 5 MB xth slice (L2-resident)
__global__ __launch_bounds__(256) void gat_aggregate2(const float* __restrict__ xth,
                                                      const float* __restrict__ al_s,
                                                      const float* __restrict__ al_d,
                                                      const int* __restrict__ offsets,
                                                      const int* __restrict__ csr,
                                                      const int* __restrict__ ei,
                                                      const float* __restrict__ bias,
                                                      unsigned short* __restrict__ outHi,
                                                      unsigned short* __restrict__ outLo) {
    const int lane = threadIdx.x & 63;
    const int n = blockIdx.x * 4 + (threadIdx.x >> 6);
    const int h = blockIdx.y;
    const int beg = offsets[n];
    const int deg = offsets[n + 1] - beg;
    const float aldv = al_d[n * HEADS + h];
    const float* __restrict__ xh = xth + (size_t)h * N_NODES * CDIM;

    float acc = 0.f, ssum = 0.f;
    for (int base = 0; base < deg; base += 64) {
        int i = base + lane;
        int srcn = 0;
        float p = 0.f;
        if (i < deg) {
            int e = csr[beg + i];
            srcn = (e < E_EDGES) ? ei[e] : (e - E_EDGES);
            float ev = al_s[srcn * HEADS + h] + aldv;
            ev = (ev >= 0.f) ? ev : 0.2f * ev;
            p = expf(ev);       // no max-subtraction: ev is O(1), fp32-safe; alpha ratio identical
        }
        float ps = p;
#pragma unroll
        for (int off = 32; off; off >>= 1) ps += __shfl_xor(ps, off);
        ssum += ps;
        int cnt = min(64, deg - base);
        int pbits = __builtin_bit_cast(int, p);
        for (int t = 0; t < cnt; ++t) {
            float a = __builtin_bit_cast(float, __builtin_amdgcn_readlane(pbits, t));
            int s2 = __builtin_amdgcn_readlane(srcn, t);
            acc = fmaf(a, xh[(size_t)s2 * CDIM + lane], acc);
        }
    }
    float v = acc / (ssum + 1e-16f) + bias[h * CDIM + lane];
    v = (v > 0.f) ? v : expm1f(v);      // ELU
    unsigned short hi = f2bf(v);
    unsigned short lo = f2bf(v - bf2f(hi));
    size_t o = (size_t)n * HID + h * CDIM + lane;
    outHi[o] = hi;
    outLo[o] = lo;
}

// ---------------------------------------------------------------- pooling
__global__ __launch_bounds__(128) void find_bounds(const int* __restrict__ batch,
                                                   int* __restrict__ bounds) {
    int b = threadIdx.x;
    if (b <= B_GRAPHS) {
        int lo = 0, hi = N_NODES;
        while (lo < hi) {
            int mid = (lo + hi) >> 1;
            if (batch[mid] < b) lo = mid + 1; else hi = mid;
        }
        bounds[b] = lo;
    }
}

__global__ __launch_bounds__(256) void pool_kernel(const unsigned short* __restrict__ hHi,
                                                   const unsigned short* __restrict__ hLo,
                                                   const int* __restrict__ bounds,
                                                   float* __restrict__ outG) {
    int b = blockIdx.x;
    int tid = threadIdx.x;
    int s = bounds[b], e = bounds[b + 1];
    float a0 = 0.f, a1 = 0.f;
    for (int n = s; n < e; ++n) {
        size_t base = (size_t)n * HID;
        a0 += bf2f(hHi[base + tid]) + bf2f(hLo[base + tid]);
        a1 += bf2f(hHi[base + tid + 256]) + bf2f(hLo[base + tid + 256]);
    }
    float cnt = fmaxf((float)(e - s), 1.0f);
    outG[b * HID + tid] = a0 / cnt;
    outG[b * HID + tid + 256] = a1 / cnt;
}

// ---------------------------------------------------------------- classifier + softmax
__global__ __launch_bounds__(64) void classifier_kernel(const float* __restrict__ hG,
                                                        const float* __restrict__ Wl,
                                                        const float* __restrict__ bl,
                                                        float* __restrict__ outP) {
    int b = blockIdx.x;
    int tid = threadIdx.x;
    __shared__ float row[HID];
    __shared__ float logit[NCLS];
    for (int j = tid; j < HID; j += 64) row[j] = hG[b * HID + j];
    __syncthreads();
    if (tid < NCLS) {
        float acc = bl[tid];
        for (int j = 0; j < HID; ++j) acc += row[j] * Wl[j * NCLS + tid];
        logit[tid] = acc;
    }
    __syncthreads();
    if (tid == 0) {
        float mx = logit[0];
        for (int k = 1; k < NCLS; ++k) mx = fmaxf(mx, logit[k]);
        float ssum = 0.f, ex[NCLS];
        for (int k = 0; k < NCLS; ++k) { ex[k] = expf(logit[k] - mx); ssum += ex[k]; }
        for (int k = 0; k < NCLS; ++k) outP[b * NCLS + k] = ex[k] / ssum;
    }
}

// ---------------------------------------------------------------- launch
extern "C" void kernel_launch(void* const* d_in, const int* in_sizes, int n_in,
                              void* d_out, int out_size, void* d_ws, size_t ws_size,
                              hipStream_t stream) {
    const float* x     = (const float*)d_in[0];
    const int*   ei    = (const int*)d_in[1];
    const int*   batch = (const int*)d_in[2];
    const float* W[3]  = { (const float*)d_in[3], (const float*)d_in[7],  (const float*)d_in[11] };
    const float* as_[3] = { (const float*)d_in[4], (const float*)d_in[8],  (const float*)d_in[12] };
    const float* ad_[3] = { (const float*)d_in[5], (const float*)d_in[9],  (const float*)d_in[13] };
    const float* bb[3] = { (const float*)d_in[6], (const float*)d_in[10], (const float*)d_in[14] };
    const float* Wl    = (const float*)d_in[15];
    const float* bl    = (const float*)d_in[16];

    // workspace layout
    char* ws = (char*)d_ws;
    unsigned short* A1hi = (unsigned short*)ws;      ws += (size_t)M_PAD * F_INF * 2;  // 10.3 MB
    unsigned short* A1lo = (unsigned short*)ws;      ws += (size_t)M_PAD * F_INF * 2;
    unsigned short* A2hi = (unsigned short*)ws;      ws += (size_t)M_PAD * HID * 2;    // 20.6 MB
    unsigned short* A2lo = (unsigned short*)ws;      ws += (size_t)M_PAD * HID * 2;
    unsigned short* Bthi = (unsigned short*)ws;      ws += (size_t)HID * HID * 2;      // 0.5 MB
    unsigned short* Btlo = (unsigned short*)ws;      ws += (size_t)HID * HID * 2;
    float* xth  = (float*)ws;                        ws += (size_t)N_NODES * HID * 4;  // 41 MB
    float* als  = (float*)ws;                        ws += (size_t)N_NODES * HEADS * 4;
    float* ald  = (float*)ws;                        ws += (size_t)N_NODES * HEADS * 4;
    int* counts  = (int*)ws;                         ws += (size_t)N_NODES * 4;
    int* offsets = (int*)ws;                         ws += (size_t)(N_NODES + 1) * 4;
    int* cursor  = (int*)ws;                         ws += (size_t)N_NODES * 4;
    int* csr     = (int*)ws;                         ws += (size_t)E_TOT * 4;
    int* bounds  = (int*)ws;                         ws += (size_t)(B_GRAPHS + 1) * 4;

    float* hG = (float*)d_out;                 // 64*512
    float* probs = (float*)d_out + (size_t)B_GRAPHS * HID;

    // ---- CSR build (identical every call; rebuilt for determinism/no-caching)
    zero_ints<<<(N_NODES + 255) / 256, 256, 0, stream>>>(counts, N_NODES);
    count_edges<<<(E_TOT + 255) / 256, 256, 0, stream>>>(ei, counts);
    scan_counts<<<1, 1024, 0, stream>>>(counts, offsets, cursor);
    scatter_edges<<<(E_TOT + 255) / 256, 256, 0, stream>>>(ei, cursor, csr);
    find_bounds<<<1, 128, 0, stream>>>(batch, bounds);
    zero_pad_rows<<<((M_PAD - N_NODES) * HID + 255) / 256, 256, 0, stream>>>(A2hi, A2lo);

    dim3 ggrid(M_PAD / 128, HID / 128);   // (157, 4)
    dim3 agrid(N_NODES / 4, HEADS);       // head slowest -> L2 locality

    // ---- layer 1 (K = 256)
    {
        long totA = (long)M_PAD * F_INF;
        split_pad<<<(int)(totA / 4 / 256), 256, 0, stream>>>(x, A1hi, A1lo, N_NODES, F_INF, totA);
        transpose_split_B<<<dim3(HID / 32, F_INF / 32), 256, 0, stream>>>(W[0], Bthi, Btlo, F_INF);
        gemm_mfma<<<ggrid, 256, 0, stream>>>(A1hi, A1lo, Bthi, Btlo, xth, N_NODES, F_INF);
        compute_al<<<N_NODES * HEADS / 4, 256, 0, stream>>>(xth, as_[0], ad_[0], als, ald);
        gat_aggregate2<<<agrid, 256, 0, stream>>>(xth, als, ald, offsets, csr, ei, bb[0], A2hi, A2lo);
    }

    // ---- layers 2,3 (K = 512)
    for (int L = 1; L < 3; ++L) {
        transpose_split_B<<<dim3(HID / 32, HID / 32), 256, 0, stream>>>(W[L], Bthi, Btlo, HID);
        gemm_mfma<<<ggrid, 256, 0, stream>>>(A2hi, A2lo, Bthi, Btlo, xth, N_NODES, HID);
        compute_al<<<N_NODES * HEADS / 4, 256, 0, stream>>>(xth, as_[L], ad_[L], als, ald);
        gat_aggregate2<<<agrid, 256, 0, stream>>>(xth, als, ald, offsets, csr, ei, bb[L], A2hi, A2lo);
    }

    // ---- pool + classify
    pool_kernel<<<B_GRAPHS, 256, 0, stream>>>(A2hi, A2lo, bounds, hG);
    classifier_kernel<<<B_GRAPHS, 64, 0, stream>>>(hG, Wl, bl, probs);
}

// Round 4
// 568.405 us; speedup vs baseline: 1.6484x; 1.6484x over previous
//
#include <hip/hip_runtime.h>
#include <hip/hip_bf16.h>
#include <math.h>

#define N_NODES  20000
#define E_EDGES  320000
#define E_TOT    (E_EDGES + N_NODES)
#define F_INF    256
#define HEADS    8
#define CDIM     64
#define HID      512
#define B_GRAPHS 64
#define NCLS     10
#define M_PAD    20096          // 157 * 128

typedef __attribute__((ext_vector_type(8))) short short8;
typedef __attribute__((ext_vector_type(4))) float f32x4;

__device__ inline unsigned short f2bf(float x) {
    unsigned u = __builtin_bit_cast(unsigned, x);
    u += 0x7fff + ((u >> 16) & 1);          // round-to-nearest-even
    return (unsigned short)(u >> 16);
}
__device__ inline float bf2f(unsigned short h) {
    unsigned u = ((unsigned)h) << 16;
    return __builtin_bit_cast(float, u);
}

#define GLOAD_LDS16(g, l) __builtin_amdgcn_global_load_lds(                     \
        (const __attribute__((address_space(1))) void*)(g),                     \
        (__attribute__((address_space(3))) void*)(l), 16, 0, 0)

// ---------------------------------------------------------------- utils
__global__ __launch_bounds__(256) void zero_ints(int* p, int n) {
    int i = blockIdx.x * 256 + threadIdx.x;
    if (i < n) p[i] = 0;
}

__global__ __launch_bounds__(256) void zero_pad_rows(unsigned short* hi, unsigned short* lo) {
    int i = blockIdx.x * 256 + threadIdx.x;
    const int tot = (M_PAD - N_NODES) * HID;
    if (i < tot) {
        hi[(size_t)N_NODES * HID + i] = 0;
        lo[(size_t)N_NODES * HID + i] = 0;
    }
}

// ---------------------------------------------------------------- fp32 -> bf16 hi/lo split (row-padded)
__global__ __launch_bounds__(256) void split_pad(const float* __restrict__ src,
                                                 unsigned short* __restrict__ hi,
                                                 unsigned short* __restrict__ lo,
                                                 int M, int K, long total) {
    long i = ((long)blockIdx.x * 256 + threadIdx.x) * 4;
    if (i >= total) return;
    int row = (int)(i / K);
    float4 v = make_float4(0.f, 0.f, 0.f, 0.f);
    if (row < M) v = *(const float4*)(src + i);
    ushort4 h, l;
    h.x = f2bf(v.x); l.x = f2bf(v.x - bf2f(h.x));
    h.y = f2bf(v.y); l.y = f2bf(v.y - bf2f(h.y));
    h.z = f2bf(v.z); l.z = f2bf(v.z - bf2f(h.z));
    h.w = f2bf(v.w); l.w = f2bf(v.w - bf2f(h.w));
    *(ushort4*)(hi + i) = h;
    *(ushort4*)(lo + i) = l;
}

// ---------------------------------------------------------------- B[K][512] -> Bt_hi/lo[512][K]
__global__ __launch_bounds__(256) void transpose_split_B(const float* __restrict__ B,
                                                         unsigned short* __restrict__ Bthi,
                                                         unsigned short* __restrict__ Btlo,
                                                         int K) {
    __shared__ float t[32][33];
    int n0 = blockIdx.x * 32, k0 = blockIdx.y * 32;
    int tx = threadIdx.x & 31, ty = threadIdx.x >> 5;     // 32 x 8
    for (int i = ty; i < 32; i += 8) t[i][tx] = B[(size_t)(k0 + i) * HID + n0 + tx];
    __syncthreads();
    for (int i = ty; i < 32; i += 8) {
        float v = t[tx][i];                                // = B[k0+tx][n0+i]
        unsigned short h = f2bf(v);
        unsigned short l = f2bf(v - bf2f(h));
        Bthi[(size_t)(n0 + i) * K + k0 + tx] = h;
        Btlo[(size_t)(n0 + i) * K + k0 + tx] = l;
    }
}

// ---------------------------------------------------------------- bf16x3 MFMA GEMM
// Outputs: xtb[N][512] bf16 (gather source) + al_s/al_d[N][8] fp32 (from fp32 acc)
__global__ __launch_bounds__(256) void gemm_mfma(const unsigned short* __restrict__ Ahi,
                                                 const unsigned short* __restrict__ Alo,
                                                 const unsigned short* __restrict__ Bhi,
                                                 const unsigned short* __restrict__ Blo,
                                                 const float* __restrict__ a_src,
                                                 const float* __restrict__ a_dst,
                                                 unsigned short* __restrict__ xtb,
                                                 float* __restrict__ al_s,
                                                 float* __restrict__ al_d,
                                                 int M, int K) {
    __shared__ short AsHi[4096], AsLo[4096], BsHi[4096], BsLo[4096]; // [128 rows][32 k] swizzled
    const int tid = threadIdx.x;
    const int w = tid >> 6, lane = tid & 63;
    const int wr = w >> 1, wc = w & 1;
    const int row0 = blockIdx.x * 128, col0 = blockIdx.y * 128;

    long offA[2], offB[2];
    int ldsU[2];
#pragma unroll
    for (int i = 0; i < 2; ++i) {
        int u = w * 128 + i * 64 + lane;
        int row = u >> 2;
        int kg = (u & 3) ^ (row & 3);
        offA[i] = ((long)(row0 + row) * K + kg * 8) * 2;   // bytes
        offB[i] = ((long)(col0 + row) * K + kg * 8) * 2;
        ldsU[i] = (w * 128 + i * 64) * 8;                  // short index of LDS base
    }

    const int r16 = lane & 15, kg = lane >> 4;
    int aOff[4], bOff[4];
#pragma unroll
    for (int i = 0; i < 4; ++i) {
        int row = wr * 64 + i * 16 + r16;
        aOff[i] = (row * 4 + (kg ^ (row & 3))) * 16;
        int col = wc * 64 + i * 16 + r16;
        bOff[i] = (col * 4 + (kg ^ (col & 3))) * 16;
    }

    const char* pAhi = (const char*)Ahi;
    const char* pAlo = (const char*)Alo;
    const char* pBhi = (const char*)Bhi;
    const char* pBlo = (const char*)Blo;

    f32x4 acc[4][4] = {};

    for (int kk = 0; kk < K; kk += 32) {
        long kb = (long)kk * 2;
        __syncthreads();
#pragma unroll
        for (int i = 0; i < 2; ++i) {
            GLOAD_LDS16(pAhi + offA[i] + kb, AsHi + ldsU[i]);
            GLOAD_LDS16(pAlo + offA[i] + kb, AsLo + ldsU[i]);
            GLOAD_LDS16(pBhi + offB[i] + kb, BsHi + ldsU[i]);
            GLOAD_LDS16(pBlo + offB[i] + kb, BsLo + ldsU[i]);
        }
        __syncthreads();

        short8 ah[4], al[4], bh[4], bl[4];
#pragma unroll
        for (int i = 0; i < 4; ++i) {
            ah[i] = *(const short8*)((const char*)AsHi + aOff[i]);
            al[i] = *(const short8*)((const char*)AsLo + aOff[i]);
            bh[i] = *(const short8*)((const char*)BsHi + bOff[i]);
            bl[i] = *(const short8*)((const char*)BsLo + bOff[i]);
        }
#pragma unroll
        for (int i = 0; i < 4; ++i)
#pragma unroll
            for (int j = 0; j < 4; ++j) {
                acc[i][j] = __builtin_amdgcn_mfma_f32_16x16x32_bf16(ah[i], bh[j], acc[i][j], 0, 0, 0);
                acc[i][j] = __builtin_amdgcn_mfma_f32_16x16x32_bf16(ah[i], bl[j], acc[i][j], 0, 0, 0);
                acc[i][j] = __builtin_amdgcn_mfma_f32_16x16x32_bf16(al[i], bh[j], acc[i][j], 0, 0, 0);
            }
    }

    // ---- epilogue. C/D layout: col=lane&15 within 16-block, row=(lane>>4)*4+r.
    // This wave's 64 cols = head h's channel block.
    const int h = (col0 >> 6) + wc;
    float asv[4], adv[4];
#pragma unroll
    for (int j = 0; j < 4; ++j) {
        asv[j] = a_src[h * CDIM + j * 16 + r16];
        adv[j] = a_dst[h * CDIM + j * 16 + r16];
    }
#pragma unroll
    for (int i = 0; i < 4; ++i) {
        int rbase = row0 + wr * 64 + i * 16 + (lane >> 4) * 4;
        // al_s / al_d: dot over the 64 channels of head h (4 j-blocks x 16 lanes)
#pragma unroll
        for (int r = 0; r < 4; ++r) {
            float ss = acc[i][0][r] * asv[0] + acc[i][1][r] * asv[1]
                     + acc[i][2][r] * asv[2] + acc[i][3][r] * asv[3];
            float dd = acc[i][0][r] * adv[0] + acc[i][1][r] * adv[1]
                     + acc[i][2][r] * adv[2] + acc[i][3][r] * adv[3];
#pragma unroll
            for (int off = 1; off < 16; off <<= 1) {
                ss += __shfl_xor(ss, off);
                dd += __shfl_xor(dd, off);
            }
            int row = rbase + r;
            if ((lane & 15) == 0 && row < M) {
                al_s[row * HEADS + h] = ss;
                al_d[row * HEADS + h] = dd;
            }
        }
        // xtb bf16 store
#pragma unroll
        for (int j = 0; j < 4; ++j) {
            int col = col0 + wc * 64 + j * 16 + r16;
#pragma unroll
            for (int r = 0; r < 4; ++r)
                if (rbase + r < M) xtb[(size_t)(rbase + r) * HID + col] = f2bf(acc[i][j][r]);
        }
    }
}

// ---------------------------------------------------------------- CSR build
__global__ __launch_bounds__(256) void count_edges(const int* __restrict__ ei,
                                                   int* __restrict__ counts) {
    int e = blockIdx.x * 256 + threadIdx.x;
    if (e < E_TOT) {
        int dst = (e < E_EDGES) ? ei[E_EDGES + e] : (e - E_EDGES);
        atomicAdd(&counts[dst], 1);
    }
}

__global__ __launch_bounds__(1024) void scan_counts(const int* __restrict__ counts,
                                                    int* __restrict__ offsets,
                                                    int* __restrict__ cursor) {
    __shared__ int sdata[1024];
    __shared__ int carry_s;
    int tid = threadIdx.x;
    if (tid == 0) { carry_s = 0; offsets[0] = 0; }
    __syncthreads();
    for (int base = 0; base < N_NODES; base += 1024) {
        int i = base + tid;
        int v = (i < N_NODES) ? counts[i] : 0;
        sdata[tid] = v;
        __syncthreads();
        for (int off = 1; off < 1024; off <<= 1) {
            int t = (tid >= off) ? sdata[tid - off] : 0;
            __syncthreads();
            sdata[tid] += t;
            __syncthreads();
        }
        int incl = sdata[tid] + carry_s;
        if (i < N_NODES) {
            offsets[i + 1] = incl;
            cursor[i] = incl - v;   // exclusive offset
        }
        __syncthreads();
        if (tid == 0) carry_s += sdata[1023];
        __syncthreads();
    }
}

__global__ __launch_bounds__(256) void scatter_edges(const int* __restrict__ ei,
                                                     int* __restrict__ cursor,
                                                     int* __restrict__ csr) {
    int e = blockIdx.x * 256 + threadIdx.x;
    if (e < E_TOT) {
        int dst = (e < E_EDGES) ? ei[E_EDGES + e] : (e - E_EDGES);
        int pos = atomicAdd(&cursor[dst], 1);
        csr[pos] = e;
    }
}

// ---------------------------------------------------------------- GAT aggregation (block per dst node, single pass,
// unnormalized softmax, bf16 row gather: thread t handles channels 2t, 2t+1)
__global__ __launch_bounds__(256) void gat_aggregate3(const unsigned short* __restrict__ xtb,
                                                      const float* __restrict__ al_s,
                                                      const float* __restrict__ al_d,
                                                      const int* __restrict__ offsets,
                                                      const int* __restrict__ csr,
                                                      const int* __restrict__ ei,
                                                      const float* __restrict__ bias,
                                                      unsigned short* __restrict__ outHi,
                                                      unsigned short* __restrict__ outLo) {
    const int n = blockIdx.x;
    const int tid = threadIdx.x;
    const int beg = offsets[n], deg = offsets[n + 1] - beg;

    __shared__ float ald_sh[HEADS];
    __shared__ float alpha_sh[32][HEADS];
    __shared__ int   src_sh[32];
    __shared__ float spart[4][HEADS];
    __shared__ float s_sh[HEADS];

    if (tid < HEADS) ald_sh[tid] = al_d[n * HEADS + tid];

    const int el = tid >> 3, hh = tid & 7;     // (edge slot, head) for p computation
    const int hch = tid >> 5;                   // head of channels 2*tid, 2*tid+1
    float psum = 0.f, acc0 = 0.f, acc1 = 0.f;

    for (int cbase = 0; cbase < deg; cbase += 32) {
        const int cnum = min(32, deg - cbase);
        __syncthreads();
        if (el < cnum) {
            int e = csr[beg + cbase + el];
            int srcn = (e < E_EDGES) ? ei[e] : (e - E_EDGES);
            if (hh == 0) src_sh[el] = srcn;
            float ev = al_s[srcn * HEADS + hh] + ald_sh[hh];
            ev = (ev >= 0.f) ? ev : 0.2f * ev;
            float p = expf(ev);                 // no max-subtraction: ev is O(1), fp32-safe
            alpha_sh[el][hh] = p;
            psum += p;
        }
        __syncthreads();
#pragma unroll 4
        for (int t = 0; t < cnum; ++t) {
            float a = alpha_sh[t][hch];
            unsigned v = *(const unsigned*)(xtb + (size_t)src_sh[t] * HID + 2 * tid);
            acc0 = fmaf(a, bf2f((unsigned short)(v & 0xffff)), acc0);
            acc1 = fmaf(a, bf2f((unsigned short)(v >> 16)), acc1);
        }
    }

    // reduce psum over threads sharing a head: lanes {hh, hh+8, ..., hh+56} per wave
    psum += __shfl_xor(psum, 8);
    psum += __shfl_xor(psum, 16);
    psum += __shfl_xor(psum, 32);
    if ((tid & 63) < 8) spart[tid >> 6][hh] = psum;
    __syncthreads();
    if (tid < 8) s_sh[tid] = spart[0][tid] + spart[1][tid] + spart[2][tid] + spart[3][tid];
    __syncthreads();

    float inv = 1.f / (s_sh[hch] + 1e-16f);
    float v0 = acc0 * inv + bias[2 * tid];
    float v1 = acc1 * inv + bias[2 * tid + 1];
    v0 = (v0 > 0.f) ? v0 : expm1f(v0);   // ELU
    v1 = (v1 > 0.f) ? v1 : expm1f(v1);
    unsigned short h0 = f2bf(v0), h1 = f2bf(v1);
    unsigned short l0 = f2bf(v0 - bf2f(h0)), l1 = f2bf(v1 - bf2f(h1));
    size_t o = (size_t)n * HID + 2 * tid;
    *(unsigned*)(outHi + o) = (unsigned)h0 | ((unsigned)h1 << 16);
    *(unsigned*)(outLo + o) = (unsigned)l0 | ((unsigned)l1 << 16);
}

// ---------------------------------------------------------------- pooling
__global__ __launch_bounds__(128) void find_bounds(const int* __restrict__ batch,
                                                   int* __restrict__ bounds) {
    int b = threadIdx.x;
    if (b <= B_GRAPHS) {
        int lo = 0, hi = N_NODES;
        while (lo < hi) {
            int mid = (lo + hi) >> 1;
            if (batch[mid] < b) lo = mid + 1; else hi = mid;
        }
        bounds[b] = lo;
    }
}

__global__ __launch_bounds__(256) void pool_kernel(const unsigned short* __restrict__ hHi,
                                                   const unsigned short* __restrict__ hLo,
                                                   const int* __restrict__ bounds,
                                                   float* __restrict__ outG) {
    int b = blockIdx.x;
    int tid = threadIdx.x;
    int s = bounds[b], e = bounds[b + 1];
    float a0 = 0.f, a1 = 0.f;
    for (int n = s; n < e; ++n) {
        size_t base = (size_t)n * HID;
        a0 += bf2f(hHi[base + tid]) + bf2f(hLo[base + tid]);
        a1 += bf2f(hHi[base + tid + 256]) + bf2f(hLo[base + tid + 256]);
    }
    float cnt = fmaxf((float)(e - s), 1.0f);
    outG[b * HID + tid] = a0 / cnt;
    outG[b * HID + tid + 256] = a1 / cnt;
}

// ---------------------------------------------------------------- classifier + softmax
__global__ __launch_bounds__(64) void classifier_kernel(const float* __restrict__ hG,
                                                        const float* __restrict__ Wl,
                                                        const float* __restrict__ bl,
                                                        float* __restrict__ outP) {
    int b = blockIdx.x;
    int tid = threadIdx.x;
    __shared__ float row[HID];
    __shared__ float logit[NCLS];
    for (int j = tid; j < HID; j += 64) row[j] = hG[b * HID + j];
    __syncthreads();
    if (tid < NCLS) {
        float acc = bl[tid];
        for (int j = 0; j < HID; ++j) acc += row[j] * Wl[j * NCLS + tid];
        logit[tid] = acc;
    }
    __syncthreads();
    if (tid == 0) {
        float mx = logit[0];
        for (int k = 1; k < NCLS; ++k) mx = fmaxf(mx, logit[k]);
        float ssum = 0.f, ex[NCLS];
        for (int k = 0; k < NCLS; ++k) { ex[k] = expf(logit[k] - mx); ssum += ex[k]; }
        for (int k = 0; k < NCLS; ++k) outP[b * NCLS + k] = ex[k] / ssum;
    }
}

// ---------------------------------------------------------------- launch
extern "C" void kernel_launch(void* const* d_in, const int* in_sizes, int n_in,
                              void* d_out, int out_size, void* d_ws, size_t ws_size,
                              hipStream_t stream) {
    const float* x     = (const float*)d_in[0];
    const int*   ei    = (const int*)d_in[1];
    const int*   batch = (const int*)d_in[2];
    const float* W[3]  = { (const float*)d_in[3], (const float*)d_in[7],  (const float*)d_in[11] };
    const float* as_[3] = { (const float*)d_in[4], (const float*)d_in[8],  (const float*)d_in[12] };
    const float* ad_[3] = { (const float*)d_in[5], (const float*)d_in[9],  (const float*)d_in[13] };
    const float* bb[3] = { (const float*)d_in[6], (const float*)d_in[10], (const float*)d_in[14] };
    const float* Wl    = (const float*)d_in[15];
    const float* bl    = (const float*)d_in[16];

    // workspace layout
    char* ws = (char*)d_ws;
    unsigned short* A1hi = (unsigned short*)ws;      ws += (size_t)M_PAD * F_INF * 2;  // 10.3 MB
    unsigned short* A1lo = (unsigned short*)ws;      ws += (size_t)M_PAD * F_INF * 2;
    unsigned short* A2hi = (unsigned short*)ws;      ws += (size_t)M_PAD * HID * 2;    // 20.6 MB
    unsigned short* A2lo = (unsigned short*)ws;      ws += (size_t)M_PAD * HID * 2;
    unsigned short* Bthi = (unsigned short*)ws;      ws += (size_t)HID * HID * 2;      // 0.5 MB
    unsigned short* Btlo = (unsigned short*)ws;      ws += (size_t)HID * HID * 2;
    unsigned short* xtb  = (unsigned short*)ws;      ws += (size_t)N_NODES * HID * 2;  // 20.5 MB
    float* als  = (float*)ws;                        ws += (size_t)N_NODES * HEADS * 4;
    float* ald  = (float*)ws;                        ws += (size_t)N_NODES * HEADS * 4;
    int* counts  = (int*)ws;                         ws += (size_t)N_NODES * 4;
    int* offsets = (int*)ws;                         ws += (size_t)(N_NODES + 1) * 4;
    int* cursor  = (int*)ws;                         ws += (size_t)N_NODES * 4;
    int* csr     = (int*)ws;                         ws += (size_t)E_TOT * 4;
    int* bounds  = (int*)ws;                         ws += (size_t)(B_GRAPHS + 1) * 4;

    float* hG = (float*)d_out;                 // 64*512
    float* probs = (float*)d_out + (size_t)B_GRAPHS * HID;

    // ---- CSR build (identical every call; rebuilt for determinism/no-caching)
    zero_ints<<<(N_NODES + 255) / 256, 256, 0, stream>>>(counts, N_NODES);
    count_edges<<<(E_TOT + 255) / 256, 256, 0, stream>>>(ei, counts);
    scan_counts<<<1, 1024, 0, stream>>>(counts, offsets, cursor);
    scatter_edges<<<(E_TOT + 255) / 256, 256, 0, stream>>>(ei, cursor, csr);
    find_bounds<<<1, 128, 0, stream>>>(batch, bounds);
    zero_pad_rows<<<((M_PAD - N_NODES) * HID + 255) / 256, 256, 0, stream>>>(A2hi, A2lo);

    dim3 ggrid(M_PAD / 128, HID / 128);   // (157, 4)

    // ---- layer 1 (K = 256)
    {
        long totA = (long)M_PAD * F_INF;
        split_pad<<<(int)(totA / 4 / 256), 256, 0, stream>>>(x, A1hi, A1lo, N_NODES, F_INF, totA);
        transpose_split_B<<<dim3(HID / 32, F_INF / 32), 256, 0, stream>>>(W[0], Bthi, Btlo, F_INF);
        gemm_mfma<<<ggrid, 256, 0, stream>>>(A1hi, A1lo, Bthi, Btlo, as_[0], ad_[0],
                                             xtb, als, ald, N_NODES, F_INF);
        gat_aggregate3<<<N_NODES, 256, 0, stream>>>(xtb, als, ald, offsets, csr, ei, bb[0], A2hi, A2lo);
    }

    // ---- layers 2,3 (K = 512)
    for (int L = 1; L < 3; ++L) {
        transpose_split_B<<<dim3(HID / 32, HID / 32), 256, 0, stream>>>(W[L], Bthi, Btlo, HID);
        gemm_mfma<<<ggrid, 256, 0, stream>>>(A2hi, A2lo, Bthi, Btlo, as_[L], ad_[L],
                                             xtb, als, ald, N_NODES, HID);
        gat_aggregate3<<<N_NODES, 256, 0, stream>>>(xtb, als, ald, offsets, csr, ei, bb[L], A2hi, A2lo);
    }

    // ---- pool + classify
    pool_kernel<<<B_GRAPHS, 256, 0, stream>>>(A2hi, A2lo, bounds, hG);
    classifier_kernel<<<B_GRAPHS, 64, 0, stream>>>(hG, Wl, bl, probs);
}

// Round 5
// 478.302 us; speedup vs baseline: 1.9589x; 1.1884x over previous
//
#include <hip/hip_runtime.h>
#include <hip/hip_bf16.h>
#include <math.h>

#define N_NODES  20000
#define E_EDGES  320000
#define E_TOT    (E_EDGES + N_NODES)
#define F_INF    256
#define HEADS    8
#define CDIM     64
#define HID      512
#define B_GRAPHS 64
#define NCLS     10
#define M_PAD    20096          // 157 * 128

typedef __attribute__((ext_vector_type(8))) short short8;
typedef __attribute__((ext_vector_type(4))) float f32x4;

__device__ inline unsigned short f2bf(float x) {
    unsigned u = __builtin_bit_cast(unsigned, x);
    u += 0x7fff + ((u >> 16) & 1);          // round-to-nearest-even
    return (unsigned short)(u >> 16);
}
__device__ inline float bf2f(unsigned short h) {
    unsigned u = ((unsigned)h) << 16;
    return __builtin_bit_cast(float, u);
}

#define GLOAD_LDS16(g, l) __builtin_amdgcn_global_load_lds(                     \
        (const __attribute__((address_space(1))) void*)(g),                     \
        (__attribute__((address_space(3))) void*)(l), 16, 0, 0)

// ---------------------------------------------------------------- utils
__global__ __launch_bounds__(256) void zero_ints(int* p, int n) {
    int i = blockIdx.x * 256 + threadIdx.x;
    if (i < n) p[i] = 0;
}

__global__ __launch_bounds__(256) void zero_pad_rows(unsigned short* hi, unsigned short* lo) {
    int i = blockIdx.x * 256 + threadIdx.x;
    const int tot = (M_PAD - N_NODES) * HID;
    if (i < tot) {
        hi[(size_t)N_NODES * HID + i] = 0;
        lo[(size_t)N_NODES * HID + i] = 0;
    }
}

// ---------------------------------------------------------------- fp32 -> bf16 hi/lo split (row-padded)
__global__ __launch_bounds__(256) void split_pad(const float* __restrict__ src,
                                                 unsigned short* __restrict__ hi,
                                                 unsigned short* __restrict__ lo,
                                                 int M, int K, long total) {
    long i = ((long)blockIdx.x * 256 + threadIdx.x) * 4;
    if (i >= total) return;
    int row = (int)(i / K);
    float4 v = make_float4(0.f, 0.f, 0.f, 0.f);
    if (row < M) v = *(const float4*)(src + i);
    ushort4 h, l;
    h.x = f2bf(v.x); l.x = f2bf(v.x - bf2f(h.x));
    h.y = f2bf(v.y); l.y = f2bf(v.y - bf2f(h.y));
    h.z = f2bf(v.z); l.z = f2bf(v.z - bf2f(h.z));
    h.w = f2bf(v.w); l.w = f2bf(v.w - bf2f(h.w));
    *(ushort4*)(hi + i) = h;
    *(ushort4*)(lo + i) = l;
}

// ---------------------------------------------------------------- B[K][512] -> Bt_hi/lo[512][K]
__global__ __launch_bounds__(256) void transpose_split_B(const float* __restrict__ B,
                                                         unsigned short* __restrict__ Bthi,
                                                         unsigned short* __restrict__ Btlo,
                                                         int K) {
    __shared__ float t[32][33];
    int n0 = blockIdx.x * 32, k0 = blockIdx.y * 32;
    int tx = threadIdx.x & 31, ty = threadIdx.x >> 5;     // 32 x 8
    for (int i = ty; i < 32; i += 8) t[i][tx] = B[(size_t)(k0 + i) * HID + n0 + tx];
    __syncthreads();
    for (int i = ty; i < 32; i += 8) {
        float v = t[tx][i];                                // = B[k0+tx][n0+i]
        unsigned short h = f2bf(v);
        unsigned short l = f2bf(v - bf2f(h));
        Bthi[(size_t)(n0 + i) * K + k0 + tx] = h;
        Btlo[(size_t)(n0 + i) * K + k0 + tx] = l;
    }
}

// ---------------------------------------------------------------- bf16x3 MFMA GEMM
// Outputs: xtb[N][512] bf16 (gather source) + al_s/al_d[N][8] fp32 (from fp32 acc)
__global__ __launch_bounds__(256) void gemm_mfma(const unsigned short* __restrict__ Ahi,
                                                 const unsigned short* __restrict__ Alo,
                                                 const unsigned short* __restrict__ Bhi,
                                                 const unsigned short* __restrict__ Blo,
                                                 const float* __restrict__ a_src,
                                                 const float* __restrict__ a_dst,
                                                 unsigned short* __restrict__ xtb,
                                                 float* __restrict__ al_s,
                                                 float* __restrict__ al_d,
                                                 int M, int K) {
    __shared__ short AsHi[4096], AsLo[4096], BsHi[4096], BsLo[4096]; // [128 rows][32 k] swizzled
    const int tid = threadIdx.x;
    const int w = tid >> 6, lane = tid & 63;
    const int wr = w >> 1, wc = w & 1;
    const int row0 = blockIdx.x * 128, col0 = blockIdx.y * 128;

    long offA[2], offB[2];
    int ldsU[2];
#pragma unroll
    for (int i = 0; i < 2; ++i) {
        int u = w * 128 + i * 64 + lane;
        int row = u >> 2;
        int kg = (u & 3) ^ (row & 3);
        offA[i] = ((long)(row0 + row) * K + kg * 8) * 2;   // bytes
        offB[i] = ((long)(col0 + row) * K + kg * 8) * 2;
        ldsU[i] = (w * 128 + i * 64) * 8;                  // short index of LDS base
    }

    const int r16 = lane & 15, kg = lane >> 4;
    int aOff[4], bOff[4];
#pragma unroll
    for (int i = 0; i < 4; ++i) {
        int row = wr * 64 + i * 16 + r16;
        aOff[i] = (row * 4 + (kg ^ (row & 3))) * 16;
        int col = wc * 64 + i * 16 + r16;
        bOff[i] = (col * 4 + (kg ^ (col & 3))) * 16;
    }

    const char* pAhi = (const char*)Ahi;
    const char* pAlo = (const char*)Alo;
    const char* pBhi = (const char*)Bhi;
    const char* pBlo = (const char*)Blo;

    f32x4 acc[4][4] = {};

    for (int kk = 0; kk < K; kk += 32) {
        long kb = (long)kk * 2;
        __syncthreads();
#pragma unroll
        for (int i = 0; i < 2; ++i) {
            GLOAD_LDS16(pAhi + offA[i] + kb, AsHi + ldsU[i]);
            GLOAD_LDS16(pAlo + offA[i] + kb, AsLo + ldsU[i]);
            GLOAD_LDS16(pBhi + offB[i] + kb, BsHi + ldsU[i]);
            GLOAD_LDS16(pBlo + offB[i] + kb, BsLo + ldsU[i]);
        }
        __syncthreads();

        short8 ah[4], al[4], bh[4], bl[4];
#pragma unroll
        for (int i = 0; i < 4; ++i) {
            ah[i] = *(const short8*)((const char*)AsHi + aOff[i]);
            al[i] = *(const short8*)((const char*)AsLo + aOff[i]);
            bh[i] = *(const short8*)((const char*)BsHi + bOff[i]);
            bl[i] = *(const short8*)((const char*)BsLo + bOff[i]);
        }
#pragma unroll
        for (int i = 0; i < 4; ++i)
#pragma unroll
            for (int j = 0; j < 4; ++j) {
                acc[i][j] = __builtin_amdgcn_mfma_f32_16x16x32_bf16(ah[i], bh[j], acc[i][j], 0, 0, 0);
                acc[i][j] = __builtin_amdgcn_mfma_f32_16x16x32_bf16(ah[i], bl[j], acc[i][j], 0, 0, 0);
                acc[i][j] = __builtin_amdgcn_mfma_f32_16x16x32_bf16(al[i], bh[j], acc[i][j], 0, 0, 0);
            }
    }

    // ---- epilogue. C/D layout: col=lane&15 within 16-block, row=(lane>>4)*4+r.
    // This wave's 64 cols = head h's channel block.
    const int h = (col0 >> 6) + wc;
    float asv[4], adv[4];
#pragma unroll
    for (int j = 0; j < 4; ++j) {
        asv[j] = a_src[h * CDIM + j * 16 + r16];
        adv[j] = a_dst[h * CDIM + j * 16 + r16];
    }
#pragma unroll
    for (int i = 0; i < 4; ++i) {
        int rbase = row0 + wr * 64 + i * 16 + (lane >> 4) * 4;
        // al_s / al_d: dot over the 64 channels of head h (4 j-blocks x 16 lanes)
#pragma unroll
        for (int r = 0; r < 4; ++r) {
            float ss = acc[i][0][r] * asv[0] + acc[i][1][r] * asv[1]
                     + acc[i][2][r] * asv[2] + acc[i][3][r] * asv[3];
            float dd = acc[i][0][r] * adv[0] + acc[i][1][r] * adv[1]
                     + acc[i][2][r] * adv[2] + acc[i][3][r] * adv[3];
#pragma unroll
            for (int off = 1; off < 16; off <<= 1) {
                ss += __shfl_xor(ss, off);
                dd += __shfl_xor(dd, off);
            }
            int row = rbase + r;
            if ((lane & 15) == 0 && row < M) {
                al_s[row * HEADS + h] = ss;
                al_d[row * HEADS + h] = dd;
            }
        }
        // xtb bf16 store
#pragma unroll
        for (int j = 0; j < 4; ++j) {
            int col = col0 + wc * 64 + j * 16 + r16;
#pragma unroll
            for (int r = 0; r < 4; ++r)
                if (rbase + r < M) xtb[(size_t)(rbase + r) * HID + col] = f2bf(acc[i][j][r]);
        }
    }
}

// ---------------------------------------------------------------- CSR build
__global__ __launch_bounds__(256) void count_edges(const int* __restrict__ ei,
                                                   int* __restrict__ counts) {
    int e = blockIdx.x * 256 + threadIdx.x;
    if (e < E_TOT) {
        int dst = (e < E_EDGES) ? ei[E_EDGES + e] : (e - E_EDGES);
        atomicAdd(&counts[dst], 1);
    }
}

__global__ __launch_bounds__(1024) void scan_counts(const int* __restrict__ counts,
                                                    int* __restrict__ offsets,
                                                    int* __restrict__ cursor) {
    __shared__ int sdata[1024];
    __shared__ int carry_s;
    int tid = threadIdx.x;
    if (tid == 0) { carry_s = 0; offsets[0] = 0; }
    __syncthreads();
    for (int base = 0; base < N_NODES; base += 1024) {
        int i = base + tid;
        int v = (i < N_NODES) ? counts[i] : 0;
        sdata[tid] = v;
        __syncthreads();
        for (int off = 1; off < 1024; off <<= 1) {
            int t = (tid >= off) ? sdata[tid - off] : 0;
            __syncthreads();
            sdata[tid] += t;
            __syncthreads();
        }
        int incl = sdata[tid] + carry_s;
        if (i < N_NODES) {
            offsets[i + 1] = incl;
            cursor[i] = incl - v;   // exclusive offset
        }
        __syncthreads();
        if (tid == 0) carry_s += sdata[1023];
        __syncthreads();
    }
}

__global__ __launch_bounds__(256) void scatter_edges(const int* __restrict__ ei,
                                                     int* __restrict__ cursor,
                                                     int* __restrict__ csr) {
    int e = blockIdx.x * 256 + threadIdx.x;
    if (e < E_TOT) {
        int dst = (e < E_EDGES) ? ei[E_EDGES + e] : (e - E_EDGES);
        int pos = atomicAdd(&cursor[dst], 1);
        csr[pos] = e;
    }
}

// ---------------------------------------------------------------- GAT aggregation (block per dst node, single pass,
// unnormalized softmax, bf16 row gather: thread t handles channels 2t, 2t+1)
__global__ __launch_bounds__(256) void gat_aggregate3(const unsigned short* __restrict__ xtb,
                                                      const float* __restrict__ al_s,
                                                      const float* __restrict__ al_d,
                                                      const int* __restrict__ offsets,
                                                      const int* __restrict__ csr,
                                                      const int* __restrict__ ei,
                                                      const float* __restrict__ bias,
                                                      unsigned short* __restrict__ outHi,
                                                      unsigned short* __restrict__ outLo) {
    const int n = blockIdx.x;
    const int tid = threadIdx.x;
    const int beg = offsets[n], deg = offsets[n + 1] - beg;

    __shared__ float ald_sh[HEADS];
    __shared__ float alpha_sh[32][HEADS];
    __shared__ int   src_sh[32];
    __shared__ float spart[4][HEADS];
    __shared__ float s_sh[HEADS];

    if (tid < HEADS) ald_sh[tid] = al_d[n * HEADS + tid];

    const int el = tid >> 3, hh = tid & 7;     // (edge slot, head) for p computation
    const int hch = tid >> 5;                   // head of channels 2*tid, 2*tid+1
    float psum = 0.f, acc0 = 0.f, acc1 = 0.f;

    for (int cbase = 0; cbase < deg; cbase += 32) {
        const int cnum = min(32, deg - cbase);
        __syncthreads();
        if (el < cnum) {
            int e = csr[beg + cbase + el];
            int srcn = (e < E_EDGES) ? ei[e] : (e - E_EDGES);
            if (hh == 0) src_sh[el] = srcn;
            float ev = al_s[srcn * HEADS + hh] + ald_sh[hh];
            ev = (ev >= 0.f) ? ev : 0.2f * ev;
            float p = expf(ev);                 // no max-subtraction: ev is O(1), fp32-safe
            alpha_sh[el][hh] = p;
            psum += p;
        }
        __syncthreads();
#pragma unroll 4
        for (int t = 0; t < cnum; ++t) {
            float a = alpha_sh[t][hch];
            unsigned v = *(const unsigned*)(xtb + (size_t)src_sh[t] * HID + 2 * tid);
            acc0 = fmaf(a, bf2f((unsigned short)(v & 0xffff)), acc0);
            acc1 = fmaf(a, bf2f((unsigned short)(v >> 16)), acc1);
        }
    }

    // reduce psum over threads sharing a head: lanes {hh, hh+8, ..., hh+56} per wave
    psum += __shfl_xor(psum, 8);
    psum += __shfl_xor(psum, 16);
    psum += __shfl_xor(psum, 32);
    if ((tid & 63) < 8) spart[tid >> 6][hh] = psum;
    __syncthreads();
    if (tid < 8) s_sh[tid] = spart[0][tid] + spart[1][tid] + spart[2][tid] + spart[3][tid];
    __syncthreads();

    float inv = 1.f / (s_sh[hch] + 1e-16f);
    float v0 = acc0 * inv + bias[2 * tid];
    float v1 = acc1 * inv + bias[2 * tid + 1];
    v0 = (v0 > 0.f) ? v0 : expm1f(v0);   // ELU
    v1 = (v1 > 0.f) ? v1 : expm1f(v1);
    unsigned short h0 = f2bf(v0), h1 = f2bf(v1);
    unsigned short l0 = f2bf(v0 - bf2f(h0)), l1 = f2bf(v1 - bf2f(h1));
    size_t o = (size_t)n * HID + 2 * tid;
    *(unsigned*)(outHi + o) = (unsigned)h0 | ((unsigned)h1 << 16);
    *(unsigned*)(outLo + o) = (unsigned)l0 | ((unsigned)l1 << 16);
}

// ---------------------------------------------------------------- pooling
__global__ __launch_bounds__(128) void find_bounds(const int* __restrict__ batch,
                                                   int* __restrict__ bounds) {
    int b = threadIdx.x;
    if (b <= B_GRAPHS) {
        int lo = 0, hi = N_NODES;
        while (lo < hi) {
            int mid = (lo + hi) >> 1;
            if (batch[mid] < b) lo = mid + 1; else hi = mid;
        }
        bounds[b] = lo;
    }
}

// stage A: grid (B_GRAPHS, 8 ch-blocks, 4 node-splits); 8 nodes in flight per block
__global__ __launch_bounds__(256) void pool_partial(const unsigned short* __restrict__ hHi,
                                                    const unsigned short* __restrict__ hLo,
                                                    const int* __restrict__ bounds,
                                                    float* __restrict__ partial) {
    const int b = blockIdx.x, y = blockIdx.y, k = blockIdx.z;
    const int s = bounds[b], cnt = bounds[b + 1] - s;
    const int ns = s + (cnt * k) / 4;
    const int ne = s + (cnt * (k + 1)) / 4;
    const int t = threadIdx.x;
    const int chp = t & 31;            // u32 pair within 64-ch block
    const int nl = t >> 5;             // 0..7

    float a0 = 0.f, a1 = 0.f;
    for (int n = ns + nl; n < ne; n += 8) {
        size_t off = (size_t)n * HID + y * 64 + chp * 2;
        unsigned vh = *(const unsigned*)(hHi + off);
        unsigned vl = *(const unsigned*)(hLo + off);
        a0 += bf2f((unsigned short)(vh & 0xffff)) + bf2f((unsigned short)(vl & 0xffff));
        a1 += bf2f((unsigned short)(vh >> 16)) + bf2f((unsigned short)(vl >> 16));
    }
    __shared__ float red[4][32][2];
    a0 += __shfl_xor(a0, 32);
    a1 += __shfl_xor(a1, 32);
    if ((t & 63) < 32) { red[t >> 6][chp][0] = a0; red[t >> 6][chp][1] = a1; }
    __syncthreads();
    if (t < 64) {
        int cp = t >> 1, c = t & 1;
        float v = red[0][cp][c] + red[1][cp][c] + red[2][cp][c] + red[3][cp][c];
        partial[(((size_t)k * B_GRAPHS + b) * 8 + y) * 64 + cp * 2 + c] = v;
    }
}

// stage B: grid B_GRAPHS x 512 threads
__global__ __launch_bounds__(512) void pool_final(const float* __restrict__ partial,
                                                  const int* __restrict__ bounds,
                                                  float* __restrict__ hG) {
    const int b = blockIdx.x, t = threadIdx.x;
    float v = 0.f;
#pragma unroll
    for (int k = 0; k < 4; ++k)
        v += partial[((size_t)k * B_GRAPHS + b) * HID + t];
    float cnt = fmaxf((float)(bounds[b + 1] - bounds[b]), 1.0f);
    hG[b * HID + t] = v / cnt;
}

// ---------------------------------------------------------------- classifier + softmax
__global__ __launch_bounds__(64) void classifier_kernel(const float* __restrict__ hG,
                                                        const float* __restrict__ Wl,
                                                        const float* __restrict__ bl,
                                                        float* __restrict__ outP) {
    int b = blockIdx.x;
    int tid = threadIdx.x;
    __shared__ float row[HID];
    __shared__ float logit[NCLS];
    for (int j = tid; j < HID; j += 64) row[j] = hG[b * HID + j];
    __syncthreads();
    if (tid < NCLS) {
        float acc = bl[tid];
        for (int j = 0; j < HID; ++j) acc += row[j] * Wl[j * NCLS + tid];
        logit[tid] = acc;
    }
    __syncthreads();
    if (tid == 0) {
        float mx = logit[0];
        for (int k = 1; k < NCLS; ++k) mx = fmaxf(mx, logit[k]);
        float ssum = 0.f, ex[NCLS];
        for (int k = 0; k < NCLS; ++k) { ex[k] = expf(logit[k] - mx); ssum += ex[k]; }
        for (int k = 0; k < NCLS; ++k) outP[b * NCLS + k] = ex[k] / ssum;
    }
}

// ---------------------------------------------------------------- launch
extern "C" void kernel_launch(void* const* d_in, const int* in_sizes, int n_in,
                              void* d_out, int out_size, void* d_ws, size_t ws_size,
                              hipStream_t stream) {
    const float* x     = (const float*)d_in[0];
    const int*   ei    = (const int*)d_in[1];
    const int*   batch = (const int*)d_in[2];
    const float* W[3]  = { (const float*)d_in[3], (const float*)d_in[7],  (const float*)d_in[11] };
    const float* as_[3] = { (const float*)d_in[4], (const float*)d_in[8],  (const float*)d_in[12] };
    const float* ad_[3] = { (const float*)d_in[5], (const float*)d_in[9],  (const float*)d_in[13] };
    const float* bb[3] = { (const float*)d_in[6], (const float*)d_in[10], (const float*)d_in[14] };
    const float* Wl    = (const float*)d_in[15];
    const float* bl    = (const float*)d_in[16];

    // workspace layout
    char* ws = (char*)d_ws;
    unsigned short* A1hi = (unsigned short*)ws;      ws += (size_t)M_PAD * F_INF * 2;  // 10.3 MB
    unsigned short* A1lo = (unsigned short*)ws;      ws += (size_t)M_PAD * F_INF * 2;
    unsigned short* A2hi = (unsigned short*)ws;      ws += (size_t)M_PAD * HID * 2;    // 20.6 MB
    unsigned short* A2lo = (unsigned short*)ws;      ws += (size_t)M_PAD * HID * 2;
    unsigned short* Bthi = (unsigned short*)ws;      ws += (size_t)HID * HID * 2;      // 0.5 MB
    unsigned short* Btlo = (unsigned short*)ws;      ws += (size_t)HID * HID * 2;
    unsigned short* xtb  = (unsigned short*)ws;      ws += (size_t)N_NODES * HID * 2;  // 20.5 MB
    float* als  = (float*)ws;                        ws += (size_t)N_NODES * HEADS * 4;
    float* ald  = (float*)ws;                        ws += (size_t)N_NODES * HEADS * 4;
    float* partial = (float*)ws;                     ws += (size_t)4 * B_GRAPHS * HID * 4; // 512 KB
    int* counts  = (int*)ws;                         ws += (size_t)N_NODES * 4;
    int* offsets = (int*)ws;                         ws += (size_t)(N_NODES + 1) * 4;
    int* cursor  = (int*)ws;                         ws += (size_t)N_NODES * 4;
    int* csr     = (int*)ws;                         ws += (size_t)E_TOT * 4;
    int* bounds  = (int*)ws;                         ws += (size_t)(B_GRAPHS + 1) * 4;

    float* hG = (float*)d_out;                 // 64*512
    float* probs = (float*)d_out + (size_t)B_GRAPHS * HID;

    // ---- CSR build (identical every call; rebuilt for determinism/no-caching)
    zero_ints<<<(N_NODES + 255) / 256, 256, 0, stream>>>(counts, N_NODES);
    count_edges<<<(E_TOT + 255) / 256, 256, 0, stream>>>(ei, counts);
    scan_counts<<<1, 1024, 0, stream>>>(counts, offsets, cursor);
    scatter_edges<<<(E_TOT + 255) / 256, 256, 0, stream>>>(ei, cursor, csr);
    find_bounds<<<1, 128, 0, stream>>>(batch, bounds);
    zero_pad_rows<<<((M_PAD - N_NODES) * HID + 255) / 256, 256, 0, stream>>>(A2hi, A2lo);

    dim3 ggrid(M_PAD / 128, HID / 128);   // (157, 4)

    // ---- layer 1 (K = 256)
    {
        long totA = (long)M_PAD * F_INF;
        split_pad<<<(int)(totA / 4 / 256), 256, 0, stream>>>(x, A1hi, A1lo, N_NODES, F_INF, totA);
        transpose_split_B<<<dim3(HID / 32, F_INF / 32), 256, 0, stream>>>(W[0], Bthi, Btlo, F_INF);
        gemm_mfma<<<ggrid, 256, 0, stream>>>(A1hi, A1lo, Bthi, Btlo, as_[0], ad_[0],
                                             xtb, als, ald, N_NODES, F_INF);
        gat_aggregate3<<<N_NODES, 256, 0, stream>>>(xtb, als, ald, offsets, csr, ei, bb[0], A2hi, A2lo);
    }

    // ---- layers 2,3 (K = 512)
    for (int L = 1; L < 3; ++L) {
        transpose_split_B<<<dim3(HID / 32, HID / 32), 256, 0, stream>>>(W[L], Bthi, Btlo, HID);
        gemm_mfma<<<ggrid, 256, 0, stream>>>(A2hi, A2lo, Bthi, Btlo, as_[L], ad_[L],
                                             xtb, als, ald, N_NODES, HID);
        gat_aggregate3<<<N_NODES, 256, 0, stream>>>(xtb, als, ald, offsets, csr, ei, bb[L], A2hi, A2lo);
    }

    // ---- pool + classify
    {
        dim3 pgrid(B_GRAPHS, 8, 4);
        pool_partial<<<pgrid, 256, 0, stream>>>(A2hi, A2lo, bounds, partial);
        pool_final<<<B_GRAPHS, 512, 0, stream>>>(partial, bounds, hG);
    }
    classifier_kernel<<<B_GRAPHS, 64, 0, stream>>>(hG, Wl, bl, probs);
}

// Round 6
// 454.943 us; speedup vs baseline: 2.0595x; 1.0513x over previous
//
#include <hip/hip_runtime.h>
#include <hip/hip_bf16.h>
#include <math.h>

#define N_NODES  20000
#define E_EDGES  320000
#define E_TOT    (E_EDGES + N_NODES)
#define F_INF    256
#define HEADS    8
#define CDIM     64
#define HID      512
#define B_GRAPHS 64
#define NCLS     10
#define M_PAD    20096          // 157 * 128
#define NSCAN    20             // ceil(20000/1024)

typedef __attribute__((ext_vector_type(8))) short short8;
typedef __attribute__((ext_vector_type(4))) float f32x4;

__device__ inline unsigned short f2bf(float x) {
    unsigned u = __builtin_bit_cast(unsigned, x);
    u += 0x7fff + ((u >> 16) & 1);          // round-to-nearest-even
    return (unsigned short)(u >> 16);
}
__device__ inline float bf2f(unsigned short h) {
    unsigned u = ((unsigned)h) << 16;
    return __builtin_bit_cast(float, u);
}

#define GLOAD_LDS16(g, l) __builtin_amdgcn_global_load_lds(                     \
        (const __attribute__((address_space(1))) void*)(g),                     \
        (__attribute__((address_space(3))) void*)(l), 16, 0, 0)

// ---------------------------------------------------------------- utils
__global__ __launch_bounds__(256) void zero_ints(int* p, int n) {
    int i = blockIdx.x * 256 + threadIdx.x;
    if (i < n) p[i] = 0;
}

__global__ __launch_bounds__(256) void zero_pad_rows(unsigned short* hi, unsigned short* lo) {
    int i = blockIdx.x * 256 + threadIdx.x;
    const int tot = (M_PAD - N_NODES) * HID;
    if (i < tot) {
        hi[(size_t)N_NODES * HID + i] = 0;
        lo[(size_t)N_NODES * HID + i] = 0;
    }
}

// ---------------------------------------------------------------- fp32 -> bf16 hi/lo split (row-padded)
__global__ __launch_bounds__(256) void split_pad(const float* __restrict__ src,
                                                 unsigned short* __restrict__ hi,
                                                 unsigned short* __restrict__ lo,
                                                 int M, int K, long total) {
    long i = ((long)blockIdx.x * 256 + threadIdx.x) * 4;
    if (i >= total) return;
    int row = (int)(i / K);
    float4 v = make_float4(0.f, 0.f, 0.f, 0.f);
    if (row < M) v = *(const float4*)(src + i);
    ushort4 h, l;
    h.x = f2bf(v.x); l.x = f2bf(v.x - bf2f(h.x));
    h.y = f2bf(v.y); l.y = f2bf(v.y - bf2f(h.y));
    h.z = f2bf(v.z); l.z = f2bf(v.z - bf2f(h.z));
    h.w = f2bf(v.w); l.w = f2bf(v.w - bf2f(h.w));
    *(ushort4*)(hi + i) = h;
    *(ushort4*)(lo + i) = l;
}

// ---------------------------------------------------------------- B[K][512] -> Bt_hi/lo[512][K]
__global__ __launch_bounds__(256) void transpose_split_B(const float* __restrict__ B,
                                                         unsigned short* __restrict__ Bthi,
                                                         unsigned short* __restrict__ Btlo,
                                                         int K) {
    __shared__ float t[32][33];
    int n0 = blockIdx.x * 32, k0 = blockIdx.y * 32;
    int tx = threadIdx.x & 31, ty = threadIdx.x >> 5;     // 32 x 8
    for (int i = ty; i < 32; i += 8) t[i][tx] = B[(size_t)(k0 + i) * HID + n0 + tx];
    __syncthreads();
    for (int i = ty; i < 32; i += 8) {
        float v = t[tx][i];                                // = B[k0+tx][n0+i]
        unsigned short h = f2bf(v);
        unsigned short l = f2bf(v - bf2f(h));
        Bthi[(size_t)(n0 + i) * K + k0 + tx] = h;
        Btlo[(size_t)(n0 + i) * K + k0 + tx] = l;
    }
}

// ---------------------------------------------------------------- bf16x3 MFMA GEMM
// Outputs: xtb[N][512] bf16 (gather source) + al_s/al_d[N][8] fp32 (from fp32 acc)
__global__ __launch_bounds__(256) void gemm_mfma(const unsigned short* __restrict__ Ahi,
                                                 const unsigned short* __restrict__ Alo,
                                                 const unsigned short* __restrict__ Bhi,
                                                 const unsigned short* __restrict__ Blo,
                                                 const float* __restrict__ a_src,
                                                 const float* __restrict__ a_dst,
                                                 unsigned short* __restrict__ xtb,
                                                 float* __restrict__ al_s,
                                                 float* __restrict__ al_d,
                                                 int M, int K) {
    __shared__ short AsHi[4096], AsLo[4096], BsHi[4096], BsLo[4096]; // [128 rows][32 k] swizzled
    const int tid = threadIdx.x;
    const int w = tid >> 6, lane = tid & 63;
    const int wr = w >> 1, wc = w & 1;
    const int row0 = blockIdx.x * 128, col0 = blockIdx.y * 128;

    long offA[2], offB[2];
    int ldsU[2];
#pragma unroll
    for (int i = 0; i < 2; ++i) {
        int u = w * 128 + i * 64 + lane;
        int row = u >> 2;
        int kg = (u & 3) ^ (row & 3);
        offA[i] = ((long)(row0 + row) * K + kg * 8) * 2;   // bytes
        offB[i] = ((long)(col0 + row) * K + kg * 8) * 2;
        ldsU[i] = (w * 128 + i * 64) * 8;                  // short index of LDS base
    }

    const int r16 = lane & 15, kg = lane >> 4;
    int aOff[4], bOff[4];
#pragma unroll
    for (int i = 0; i < 4; ++i) {
        int row = wr * 64 + i * 16 + r16;
        aOff[i] = (row * 4 + (kg ^ (row & 3))) * 16;
        int col = wc * 64 + i * 16 + r16;
        bOff[i] = (col * 4 + (kg ^ (col & 3))) * 16;
    }

    const char* pAhi = (const char*)Ahi;
    const char* pAlo = (const char*)Alo;
    const char* pBhi = (const char*)Bhi;
    const char* pBlo = (const char*)Blo;

    f32x4 acc[4][4] = {};

    for (int kk = 0; kk < K; kk += 32) {
        long kb = (long)kk * 2;
        __syncthreads();
#pragma unroll
        for (int i = 0; i < 2; ++i) {
            GLOAD_LDS16(pAhi + offA[i] + kb, AsHi + ldsU[i]);
            GLOAD_LDS16(pAlo + offA[i] + kb, AsLo + ldsU[i]);
            GLOAD_LDS16(pBhi + offB[i] + kb, BsHi + ldsU[i]);
            GLOAD_LDS16(pBlo + offB[i] + kb, BsLo + ldsU[i]);
        }
        __syncthreads();

        short8 ah[4], al[4], bh[4], bl[4];
#pragma unroll
        for (int i = 0; i < 4; ++i) {
            ah[i] = *(const short8*)((const char*)AsHi + aOff[i]);
            al[i] = *(const short8*)((const char*)AsLo + aOff[i]);
            bh[i] = *(const short8*)((const char*)BsHi + bOff[i]);
            bl[i] = *(const short8*)((const char*)BsLo + bOff[i]);
        }
#pragma unroll
        for (int i = 0; i < 4; ++i)
#pragma unroll
            for (int j = 0; j < 4; ++j) {
                acc[i][j] = __builtin_amdgcn_mfma_f32_16x16x32_bf16(ah[i], bh[j], acc[i][j], 0, 0, 0);
                acc[i][j] = __builtin_amdgcn_mfma_f32_16x16x32_bf16(ah[i], bl[j], acc[i][j], 0, 0, 0);
                acc[i][j] = __builtin_amdgcn_mfma_f32_16x16x32_bf16(al[i], bh[j], acc[i][j], 0, 0, 0);
            }
    }

    // ---- epilogue. C/D layout: col=lane&15 within 16-block, row=(lane>>4)*4+r.
    // This wave's 64 cols = head h's channel block.
    const int h = (col0 >> 6) + wc;
    float asv[4], adv[4];
#pragma unroll
    for (int j = 0; j < 4; ++j) {
        asv[j] = a_src[h * CDIM + j * 16 + r16];
        adv[j] = a_dst[h * CDIM + j * 16 + r16];
    }
#pragma unroll
    for (int i = 0; i < 4; ++i) {
        int rbase = row0 + wr * 64 + i * 16 + (lane >> 4) * 4;
        // al_s / al_d: dot over the 64 channels of head h (4 j-blocks x 16 lanes)
#pragma unroll
        for (int r = 0; r < 4; ++r) {
            float ss = acc[i][0][r] * asv[0] + acc[i][1][r] * asv[1]
                     + acc[i][2][r] * asv[2] + acc[i][3][r] * asv[3];
            float dd = acc[i][0][r] * adv[0] + acc[i][1][r] * adv[1]
                     + acc[i][2][r] * adv[2] + acc[i][3][r] * adv[3];
#pragma unroll
            for (int off = 1; off < 16; off <<= 1) {
                ss += __shfl_xor(ss, off);
                dd += __shfl_xor(dd, off);
            }
            int row = rbase + r;
            if ((lane & 15) == 0 && row < M) {
                al_s[row * HEADS + h] = ss;
                al_d[row * HEADS + h] = dd;
            }
        }
        // xtb bf16 store
#pragma unroll
        for (int j = 0; j < 4; ++j) {
            int col = col0 + wc * 64 + j * 16 + r16;
#pragma unroll
            for (int r = 0; r < 4; ++r)
                if (rbase + r < M) xtb[(size_t)(rbase + r) * HID + col] = f2bf(acc[i][j][r]);
        }
    }
}

// ---------------------------------------------------------------- CSR build
__global__ __launch_bounds__(256) void count_edges(const int* __restrict__ ei,
                                                   int* __restrict__ counts) {
    int e = blockIdx.x * 256 + threadIdx.x;
    if (e < E_TOT) {
        int dst = (e < E_EDGES) ? ei[E_EDGES + e] : (e - E_EDGES);
        atomicAdd(&counts[dst], 1);
    }
}

// parallel 3-phase scan
__global__ __launch_bounds__(1024) void scan_local(const int* __restrict__ counts,
                                                   int* __restrict__ incl,
                                                   int* __restrict__ bsum) {
    __shared__ int s[1024];
    int tid = threadIdx.x;
    int i = blockIdx.x * 1024 + tid;
    int v = (i < N_NODES) ? counts[i] : 0;
    s[tid] = v;
    __syncthreads();
    for (int off = 1; off < 1024; off <<= 1) {
        int t = (tid >= off) ? s[tid - off] : 0;
        __syncthreads();
        s[tid] += t;
        __syncthreads();
    }
    if (i < N_NODES) incl[i] = s[tid];
    if (tid == 1023) bsum[blockIdx.x] = s[1023];
}

__global__ __launch_bounds__(64) void scan_bsums(const int* __restrict__ bsum,
                                                 int* __restrict__ bpre) {
    int lane = threadIdx.x;
    int v = (lane < NSCAN) ? bsum[lane] : 0;
    int incl = v;
#pragma unroll
    for (int off = 1; off < 32; off <<= 1) {
        int t = __shfl_up(incl, off);
        if (lane >= off) incl += t;
    }
    if (lane < NSCAN) bpre[lane] = incl - v;
}

__global__ __launch_bounds__(1024) void scan_finalize(const int* __restrict__ counts,
                                                      const int* __restrict__ incl,
                                                      const int* __restrict__ bpre,
                                                      int* __restrict__ offsets,
                                                      int* __restrict__ cursor) {
    int i = blockIdx.x * 1024 + threadIdx.x;
    if (i < N_NODES) {
        int inc = incl[i] + bpre[blockIdx.x];
        offsets[i + 1] = inc;
        cursor[i] = inc - counts[i];
    }
    if (i == 0) offsets[0] = 0;
}

__global__ __launch_bounds__(256) void scatter_edges(const int* __restrict__ ei,
                                                     int* __restrict__ cursor,
                                                     int* __restrict__ csr) {
    int e = blockIdx.x * 256 + threadIdx.x;
    if (e < E_TOT) {
        int dst = (e < E_EDGES) ? ei[E_EDGES + e] : (e - E_EDGES);
        int pos = atomicAdd(&cursor[dst], 1);
        csr[pos] = e;
    }
}

// ---------------------------------------------------------------- GAT aggregation: wave per node, lane owns 8 channels
// No LDS, no barriers. The 8 lanes of one head redundantly compute identical psum (no reduction needed).
__global__ __launch_bounds__(256) void gat_aggregate4(const unsigned short* __restrict__ xtb,
                                                      const float* __restrict__ al_s,
                                                      const float* __restrict__ al_d,
                                                      const int* __restrict__ offsets,
                                                      const int* __restrict__ csr,
                                                      const int* __restrict__ ei,
                                                      const float* __restrict__ bias,
                                                      unsigned short* __restrict__ outHi,
                                                      unsigned short* __restrict__ outLo) {
    const int lane = threadIdx.x & 63;
    const int n = blockIdx.x * 4 + (threadIdx.x >> 6);
    const int h = lane >> 3;            // head of this lane's channels
    const int c0 = lane * 8;            // channels c0..c0+7
    const int beg = offsets[n];
    const int deg = offsets[n + 1] - beg;
    const float aldv = al_d[n * HEADS + h];

    float acc[8] = {};
    float psum = 0.f;

#pragma unroll 4
    for (int i = 0; i < deg; ++i) {
        int e = csr[beg + i];                               // broadcast
        int srcn = (e < E_EDGES) ? ei[e] : (e - E_EDGES);   // broadcast
        float ev = al_s[srcn * HEADS + h] + aldv;
        ev = (ev >= 0.f) ? ev : 0.2f * ev;
        float p = expf(ev);         // no max-subtraction: ev is O(1), fp32-safe
        psum += p;
        short8 row = *(const short8*)(xtb + (size_t)srcn * HID + c0);
#pragma unroll
        for (int j = 0; j < 8; ++j)
            acc[j] = fmaf(p, bf2f((unsigned short)row[j]), acc[j]);
    }

    const float inv = 1.f / (psum + 1e-16f);
    float4 b0 = *(const float4*)(bias + c0);
    float4 b1 = *(const float4*)(bias + c0 + 4);
    float bv[8] = { b0.x, b0.y, b0.z, b0.w, b1.x, b1.y, b1.z, b1.w };
    short8 h8, l8;
#pragma unroll
    for (int j = 0; j < 8; ++j) {
        float v = acc[j] * inv + bv[j];
        v = (v > 0.f) ? v : expm1f(v);      // ELU
        unsigned short hi = f2bf(v);
        h8[j] = (short)hi;
        l8[j] = (short)f2bf(v - bf2f(hi));
    }
    size_t o = (size_t)n * HID + c0;
    *(short8*)(outHi + o) = h8;
    *(short8*)(outLo + o) = l8;
}

// ---------------------------------------------------------------- pooling
__global__ __launch_bounds__(128) void find_bounds(const int* __restrict__ batch,
                                                   int* __restrict__ bounds) {
    int b = threadIdx.x;
    if (b <= B_GRAPHS) {
        int lo = 0, hi = N_NODES;
        while (lo < hi) {
            int mid = (lo + hi) >> 1;
            if (batch[mid] < b) lo = mid + 1; else hi = mid;
        }
        bounds[b] = lo;
    }
}

// stage A: grid (B_GRAPHS, 8 ch-blocks, 4 node-splits); 8 nodes in flight per block
__global__ __launch_bounds__(256) void pool_partial(const unsigned short* __restrict__ hHi,
                                                    const unsigned short* __restrict__ hLo,
                                                    const int* __restrict__ bounds,
                                                    float* __restrict__ partial) {
    const int b = blockIdx.x, y = blockIdx.y, k = blockIdx.z;
    const int s = bounds[b], cnt = bounds[b + 1] - s;
    const int ns = s + (cnt * k) / 4;
    const int ne = s + (cnt * (k + 1)) / 4;
    const int t = threadIdx.x;
    const int chp = t & 31;            // u32 pair within 64-ch block
    const int nl = t >> 5;             // 0..7

    float a0 = 0.f, a1 = 0.f;
    for (int n = ns + nl; n < ne; n += 8) {
        size_t off = (size_t)n * HID + y * 64 + chp * 2;
        unsigned vh = *(const unsigned*)(hHi + off);
        unsigned vl = *(const unsigned*)(hLo + off);
        a0 += bf2f((unsigned short)(vh & 0xffff)) + bf2f((unsigned short)(vl & 0xffff));
        a1 += bf2f((unsigned short)(vh >> 16)) + bf2f((unsigned short)(vl >> 16));
    }
    __shared__ float red[4][32][2];
    a0 += __shfl_xor(a0, 32);
    a1 += __shfl_xor(a1, 32);
    if ((t & 63) < 32) { red[t >> 6][chp][0] = a0; red[t >> 6][chp][1] = a1; }
    __syncthreads();
    if (t < 64) {
        int cp = t >> 1, c = t & 1;
        float v = red[0][cp][c] + red[1][cp][c] + red[2][cp][c] + red[3][cp][c];
        partial[(((size_t)k * B_GRAPHS + b) * 8 + y) * 64 + cp * 2 + c] = v;
    }
}

// stage B: grid B_GRAPHS x 512 threads
__global__ __launch_bounds__(512) void pool_final(const float* __restrict__ partial,
                                                  const int* __restrict__ bounds,
                                                  float* __restrict__ hG) {
    const int b = blockIdx.x, t = threadIdx.x;
    float v = 0.f;
#pragma unroll
    for (int k = 0; k < 4; ++k)
        v += partial[((size_t)k * B_GRAPHS + b) * HID + t];
    float cnt = fmaxf((float)(bounds[b + 1] - bounds[b]), 1.0f);
    hG[b * HID + t] = v / cnt;
}

// ---------------------------------------------------------------- classifier + softmax
__global__ __launch_bounds__(64) void classifier_kernel(const float* __restrict__ hG,
                                                        const float* __restrict__ Wl,
                                                        const float* __restrict__ bl,
                                                        float* __restrict__ outP) {
    int b = blockIdx.x;
    int tid = threadIdx.x;
    __shared__ float row[HID];
    __shared__ float logit[NCLS];
    for (int j = tid; j < HID; j += 64) row[j] = hG[b * HID + j];
    __syncthreads();
    if (tid < NCLS) {
        float acc = bl[tid];
        for (int j = 0; j < HID; ++j) acc += row[j] * Wl[j * NCLS + tid];
        logit[tid] = acc;
    }
    __syncthreads();
    if (tid == 0) {
        float mx = logit[0];
        for (int k = 1; k < NCLS; ++k) mx = fmaxf(mx, logit[k]);
        float ssum = 0.f, ex[NCLS];
        for (int k = 0; k < NCLS; ++k) { ex[k] = expf(logit[k] - mx); ssum += ex[k]; }
        for (int k = 0; k < NCLS; ++k) outP[b * NCLS + k] = ex[k] / ssum;
    }
}

// ---------------------------------------------------------------- launch
extern "C" void kernel_launch(void* const* d_in, const int* in_sizes, int n_in,
                              void* d_out, int out_size, void* d_ws, size_t ws_size,
                              hipStream_t stream) {
    const float* x     = (const float*)d_in[0];
    const int*   ei    = (const int*)d_in[1];
    const int*   batch = (const int*)d_in[2];
    const float* W[3]  = { (const float*)d_in[3], (const float*)d_in[7],  (const float*)d_in[11] };
    const float* as_[3] = { (const float*)d_in[4], (const float*)d_in[8],  (const float*)d_in[12] };
    const float* ad_[3] = { (const float*)d_in[5], (const float*)d_in[9],  (const float*)d_in[13] };
    const float* bb[3] = { (const float*)d_in[6], (const float*)d_in[10], (const float*)d_in[14] };
    const float* Wl    = (const float*)d_in[15];
    const float* bl    = (const float*)d_in[16];

    // workspace layout
    char* ws = (char*)d_ws;
    unsigned short* A1hi = (unsigned short*)ws;      ws += (size_t)M_PAD * F_INF * 2;  // 10.3 MB
    unsigned short* A1lo = (unsigned short*)ws;      ws += (size_t)M_PAD * F_INF * 2;
    unsigned short* A2hi = (unsigned short*)ws;      ws += (size_t)M_PAD * HID * 2;    // 20.6 MB
    unsigned short* A2lo = (unsigned short*)ws;      ws += (size_t)M_PAD * HID * 2;
    unsigned short* Bthi = (unsigned short*)ws;      ws += (size_t)HID * HID * 2;      // 0.5 MB
    unsigned short* Btlo = (unsigned short*)ws;      ws += (size_t)HID * HID * 2;
    unsigned short* xtb  = (unsigned short*)ws;      ws += (size_t)N_NODES * HID * 2;  // 20.5 MB
    float* als  = (float*)ws;                        ws += (size_t)N_NODES * HEADS * 4;
    float* ald  = (float*)ws;                        ws += (size_t)N_NODES * HEADS * 4;
    float* partial = (float*)ws;                     ws += (size_t)4 * B_GRAPHS * HID * 4; // 512 KB
    int* counts  = (int*)ws;                         ws += (size_t)N_NODES * 4;
    int* incl    = (int*)ws;                         ws += (size_t)N_NODES * 4;
    int* bsum    = (int*)ws;                         ws += 32 * 4;
    int* bpre    = (int*)ws;                         ws += 32 * 4;
    int* offsets = (int*)ws;                         ws += (size_t)(N_NODES + 1) * 4;
    int* cursor  = (int*)ws;                         ws += (size_t)N_NODES * 4;
    int* csr     = (int*)ws;                         ws += (size_t)E_TOT * 4;
    int* bounds  = (int*)ws;                         ws += (size_t)(B_GRAPHS + 1) * 4;

    float* hG = (float*)d_out;                 // 64*512
    float* probs = (float*)d_out + (size_t)B_GRAPHS * HID;

    // ---- CSR build (identical every call; rebuilt for determinism/no-caching)
    zero_ints<<<(N_NODES + 255) / 256, 256, 0, stream>>>(counts, N_NODES);
    count_edges<<<(E_TOT + 255) / 256, 256, 0, stream>>>(ei, counts);
    scan_local<<<NSCAN, 1024, 0, stream>>>(counts, incl, bsum);
    scan_bsums<<<1, 64, 0, stream>>>(bsum, bpre);
    scan_finalize<<<NSCAN, 1024, 0, stream>>>(counts, incl, bpre, offsets, cursor);
    scatter_edges<<<(E_TOT + 255) / 256, 256, 0, stream>>>(ei, cursor, csr);
    find_bounds<<<1, 128, 0, stream>>>(batch, bounds);
    zero_pad_rows<<<((M_PAD - N_NODES) * HID + 255) / 256, 256, 0, stream>>>(A2hi, A2lo);

    dim3 ggrid(M_PAD / 128, HID / 128);   // (157, 4)

    // ---- layer 1 (K = 256)
    {
        long totA = (long)M_PAD * F_INF;
        split_pad<<<(int)(totA / 4 / 256), 256, 0, stream>>>(x, A1hi, A1lo, N_NODES, F_INF, totA);
        transpose_split_B<<<dim3(HID / 32, F_INF / 32), 256, 0, stream>>>(W[0], Bthi, Btlo, F_INF);
        gemm_mfma<<<ggrid, 256, 0, stream>>>(A1hi, A1lo, Bthi, Btlo, as_[0], ad_[0],
                                             xtb, als, ald, N_NODES, F_INF);
        gat_aggregate4<<<N_NODES / 4, 256, 0, stream>>>(xtb, als, ald, offsets, csr, ei, bb[0], A2hi, A2lo);
    }

    // ---- layers 2,3 (K = 512)
    for (int L = 1; L < 3; ++L) {
        transpose_split_B<<<dim3(HID / 32, HID / 32), 256, 0, stream>>>(W[L], Bthi, Btlo, HID);
        gemm_mfma<<<ggrid, 256, 0, stream>>>(A2hi, A2lo, Bthi, Btlo, as_[L], ad_[L],
                                             xtb, als, ald, N_NODES, HID);
        gat_aggregate4<<<N_NODES / 4, 256, 0, stream>>>(xtb, als, ald, offsets, csr, ei, bb[L], A2hi, A2lo);
    }

    // ---- pool + classify
    {
        dim3 pgrid(B_GRAPHS, 8, 4);
        pool_partial<<<pgrid, 256, 0, stream>>>(A2hi, A2lo, bounds, partial);
        pool_final<<<B_GRAPHS, 512, 0, stream>>>(partial, bounds, hG);
    }
    classifier_kernel<<<B_GRAPHS, 64, 0, stream>>>(hG, Wl, bl, probs);
}

// Round 7
// 435.993 us; speedup vs baseline: 2.1490x; 1.0435x over previous
//
#include <hip/hip_runtime.h>
#include <hip/hip_bf16.h>
#include <math.h>

#define N_NODES  20000
#define E_EDGES  320000
#define E_TOT    (E_EDGES + N_NODES)
#define F_INF    256
#define HEADS    8
#define CDIM     64
#define HID      512
#define B_GRAPHS 64
#define NCLS     10
#define M_PAD    20096          // 157 * 128
#define NSCAN    20             // ceil(20000/1024)

typedef __attribute__((ext_vector_type(8))) short short8;
typedef __attribute__((ext_vector_type(4))) float f32x4;

__device__ inline unsigned short f2bf(float x) {
    unsigned u = __builtin_bit_cast(unsigned, x);
    u += 0x7fff + ((u >> 16) & 1);          // round-to-nearest-even
    return (unsigned short)(u >> 16);
}
__device__ inline float bf2f(unsigned short h) {
    unsigned u = ((unsigned)h) << 16;
    return __builtin_bit_cast(float, u);
}

#define GLOAD_LDS16(g, l) __builtin_amdgcn_global_load_lds(                     \
        (const __attribute__((address_space(1))) void*)(g),                     \
        (__attribute__((address_space(3))) void*)(l), 16, 0, 0)

// ---------------------------------------------------------------- utils
__global__ __launch_bounds__(256) void zero_ints(int* p, int n) {
    int i = blockIdx.x * 256 + threadIdx.x;
    if (i < n) p[i] = 0;
}

__global__ __launch_bounds__(256) void zero_pad_rows(unsigned short* hi, unsigned short* lo) {
    int i = blockIdx.x * 256 + threadIdx.x;
    const int tot = (M_PAD - N_NODES) * HID;
    if (i < tot) {
        hi[(size_t)N_NODES * HID + i] = 0;
        lo[(size_t)N_NODES * HID + i] = 0;
    }
}

// ---------------------------------------------------------------- fp32 -> bf16 hi/lo split (row-padded)
__global__ __launch_bounds__(256) void split_pad(const float* __restrict__ src,
                                                 unsigned short* __restrict__ hi,
                                                 unsigned short* __restrict__ lo,
                                                 int M, int K, long total) {
    long i = ((long)blockIdx.x * 256 + threadIdx.x) * 4;
    if (i >= total) return;
    int row = (int)(i / K);
    float4 v = make_float4(0.f, 0.f, 0.f, 0.f);
    if (row < M) v = *(const float4*)(src + i);
    ushort4 h, l;
    h.x = f2bf(v.x); l.x = f2bf(v.x - bf2f(h.x));
    h.y = f2bf(v.y); l.y = f2bf(v.y - bf2f(h.y));
    h.z = f2bf(v.z); l.z = f2bf(v.z - bf2f(h.z));
    h.w = f2bf(v.w); l.w = f2bf(v.w - bf2f(h.w));
    *(ushort4*)(hi + i) = h;
    *(ushort4*)(lo + i) = l;
}

// ---------------------------------------------------------------- B[K][512] -> Bt_hi/lo[512][K]
__global__ __launch_bounds__(256) void transpose_split_B(const float* __restrict__ B,
                                                         unsigned short* __restrict__ Bthi,
                                                         unsigned short* __restrict__ Btlo,
                                                         int K) {
    __shared__ float t[32][33];
    int n0 = blockIdx.x * 32, k0 = blockIdx.y * 32;
    int tx = threadIdx.x & 31, ty = threadIdx.x >> 5;     // 32 x 8
    for (int i = ty; i < 32; i += 8) t[i][tx] = B[(size_t)(k0 + i) * HID + n0 + tx];
    __syncthreads();
    for (int i = ty; i < 32; i += 8) {
        float v = t[tx][i];                                // = B[k0+tx][n0+i]
        unsigned short h = f2bf(v);
        unsigned short l = f2bf(v - bf2f(h));
        Bthi[(size_t)(n0 + i) * K + k0 + tx] = h;
        Btlo[(size_t)(n0 + i) * K + k0 + tx] = l;
    }
}

// ---------------------------------------------------------------- bf16x3 MFMA GEMM, double-buffered pipeline
// Outputs: xtb[N][512] bf16 (gather source) + al_s/al_d[N][8] fp32 (from fp32 acc)
__global__ __launch_bounds__(256) void gemm_mfma(const unsigned short* __restrict__ Ahi,
                                                 const unsigned short* __restrict__ Alo,
                                                 const unsigned short* __restrict__ Bhi,
                                                 const unsigned short* __restrict__ Blo,
                                                 const float* __restrict__ a_src,
                                                 const float* __restrict__ a_dst,
                                                 unsigned short* __restrict__ xtb,
                                                 float* __restrict__ al_s,
                                                 float* __restrict__ al_d,
                                                 int M, int K) {
    __shared__ short AsHi[2][4096], AsLo[2][4096], BsHi[2][4096], BsLo[2][4096]; // 64 KB
    const int tid = threadIdx.x;
    const int w = tid >> 6, lane = tid & 63;
    const int wr = w >> 1, wc = w & 1;
    const int row0 = blockIdx.x * 128, col0 = blockIdx.y * 128;

    long offA[2], offB[2];
    int ldsU[2];
#pragma unroll
    for (int i = 0; i < 2; ++i) {
        int u = w * 128 + i * 64 + lane;
        int row = u >> 2;
        int kg = (u & 3) ^ (row & 3);
        offA[i] = ((long)(row0 + row) * K + kg * 8) * 2;   // bytes
        offB[i] = ((long)(col0 + row) * K + kg * 8) * 2;
        ldsU[i] = (w * 128 + i * 64) * 8;                  // short index of LDS base
    }

    const int r16 = lane & 15, kg = lane >> 4;
    int aOff[4], bOff[4];
#pragma unroll
    for (int i = 0; i < 4; ++i) {
        int row = wr * 64 + i * 16 + r16;
        aOff[i] = (row * 4 + (kg ^ (row & 3))) * 16;
        int col = wc * 64 + i * 16 + r16;
        bOff[i] = (col * 4 + (kg ^ (col & 3))) * 16;
    }

    const char* pAhi = (const char*)Ahi;
    const char* pAlo = (const char*)Alo;
    const char* pBhi = (const char*)Bhi;
    const char* pBlo = (const char*)Blo;

    f32x4 acc[4][4] = {};

#define STAGE(buf, kk) do {                                                      \
        long kb = (long)(kk) * 64;                                               \
        _Pragma("unroll")                                                        \
        for (int i_ = 0; i_ < 2; ++i_) {                                         \
            GLOAD_LDS16(pAhi + offA[i_] + kb, &AsHi[buf][ldsU[i_]]);             \
            GLOAD_LDS16(pAlo + offA[i_] + kb, &AsLo[buf][ldsU[i_]]);             \
            GLOAD_LDS16(pBhi + offB[i_] + kb, &BsHi[buf][ldsU[i_]]);             \
            GLOAD_LDS16(pBlo + offB[i_] + kb, &BsLo[buf][ldsU[i_]]);             \
        }                                                                        \
    } while (0)

#define COMPUTE(buf) do {                                                        \
        short8 fah[4], fal[4], fbh[4], fbl[4];                                   \
        _Pragma("unroll")                                                        \
        for (int i_ = 0; i_ < 4; ++i_) {                                         \
            fah[i_] = *(const short8*)((const char*)AsHi[buf] + aOff[i_]);       \
            fal[i_] = *(const short8*)((const char*)AsLo[buf] + aOff[i_]);       \
            fbh[i_] = *(const short8*)((const char*)BsHi[buf] + bOff[i_]);       \
            fbl[i_] = *(const short8*)((const char*)BsLo[buf] + bOff[i_]);       \
        }                                                                        \
        _Pragma("unroll")                                                        \
        for (int i_ = 0; i_ < 4; ++i_)                                           \
            _Pragma("unroll")                                                    \
            for (int j_ = 0; j_ < 4; ++j_) {                                     \
                acc[i_][j_] = __builtin_amdgcn_mfma_f32_16x16x32_bf16(fah[i_], fbh[j_], acc[i_][j_], 0, 0, 0); \
                acc[i_][j_] = __builtin_amdgcn_mfma_f32_16x16x32_bf16(fah[i_], fbl[j_], acc[i_][j_], 0, 0, 0); \
                acc[i_][j_] = __builtin_amdgcn_mfma_f32_16x16x32_bf16(fal[i_], fbh[j_], acc[i_][j_], 0, 0, 0); \
            }                                                                    \
    } while (0)

    const int NS = K >> 5;
    // prologue: stage tile 0, drain, barrier
    STAGE(0, 0);
    asm volatile("s_waitcnt vmcnt(0)" ::: "memory");
    __builtin_amdgcn_s_barrier();
    int cur = 0;
    for (int t = 0; t < NS - 1; ++t) {
        STAGE(cur ^ 1, t + 1);          // issue next tile BEFORE compute -> latency hides under MFMA
        COMPUTE(cur);
        asm volatile("s_waitcnt vmcnt(0)" ::: "memory");   // next tile landed (overlapped)
        __builtin_amdgcn_s_barrier();
        cur ^= 1;
    }
    COMPUTE(cur);                        // epilogue tile, no prefetch

#undef STAGE
#undef COMPUTE

    // ---- epilogue. C/D layout: col=lane&15 within 16-block, row=(lane>>4)*4+r.
    // This wave's 64 cols = head h's channel block.
    const int h = (col0 >> 6) + wc;
    float asv[4], adv[4];
#pragma unroll
    for (int j = 0; j < 4; ++j) {
        asv[j] = a_src[h * CDIM + j * 16 + r16];
        adv[j] = a_dst[h * CDIM + j * 16 + r16];
    }
#pragma unroll
    for (int i = 0; i < 4; ++i) {
        int rbase = row0 + wr * 64 + i * 16 + (lane >> 4) * 4;
        // al_s / al_d: dot over the 64 channels of head h (4 j-blocks x 16 lanes)
#pragma unroll
        for (int r = 0; r < 4; ++r) {
            float ss = acc[i][0][r] * asv[0] + acc[i][1][r] * asv[1]
                     + acc[i][2][r] * asv[2] + acc[i][3][r] * asv[3];
            float dd = acc[i][0][r] * adv[0] + acc[i][1][r] * adv[1]
                     + acc[i][2][r] * adv[2] + acc[i][3][r] * adv[3];
#pragma unroll
            for (int off = 1; off < 16; off <<= 1) {
                ss += __shfl_xor(ss, off);
                dd += __shfl_xor(dd, off);
            }
            int row = rbase + r;
            if ((lane & 15) == 0 && row < M) {
                al_s[row * HEADS + h] = ss;
                al_d[row * HEADS + h] = dd;
            }
        }
        // xtb bf16 store
#pragma unroll
        for (int j = 0; j < 4; ++j) {
            int col = col0 + wc * 64 + j * 16 + r16;
#pragma unroll
            for (int r = 0; r < 4; ++r)
                if (rbase + r < M) xtb[(size_t)(rbase + r) * HID + col] = f2bf(acc[i][j][r]);
        }
    }
}

// ---------------------------------------------------------------- CSR build
__global__ __launch_bounds__(256) void count_edges(const int* __restrict__ ei,
                                                   int* __restrict__ counts) {
    int e = blockIdx.x * 256 + threadIdx.x;
    if (e < E_TOT) {
        int dst = (e < E_EDGES) ? ei[E_EDGES + e] : (e - E_EDGES);
        atomicAdd(&counts[dst], 1);
    }
}

// parallel 3-phase scan
__global__ __launch_bounds__(1024) void scan_local(const int* __restrict__ counts,
                                                   int* __restrict__ incl,
                                                   int* __restrict__ bsum) {
    __shared__ int s[1024];
    int tid = threadIdx.x;
    int i = blockIdx.x * 1024 + tid;
    int v = (i < N_NODES) ? counts[i] : 0;
    s[tid] = v;
    __syncthreads();
    for (int off = 1; off < 1024; off <<= 1) {
        int t = (tid >= off) ? s[tid - off] : 0;
        __syncthreads();
        s[tid] += t;
        __syncthreads();
    }
    if (i < N_NODES) incl[i] = s[tid];
    if (tid == 1023) bsum[blockIdx.x] = s[1023];
}

__global__ __launch_bounds__(64) void scan_bsums(const int* __restrict__ bsum,
                                                 int* __restrict__ bpre) {
    int lane = threadIdx.x;
    int v = (lane < NSCAN) ? bsum[lane] : 0;
    int incl = v;
#pragma unroll
    for (int off = 1; off < 32; off <<= 1) {
        int t = __shfl_up(incl, off);
        if (lane >= off) incl += t;
    }
    if (lane < NSCAN) bpre[lane] = incl - v;
}

__global__ __launch_bounds__(1024) void scan_finalize(const int* __restrict__ counts,
                                                      const int* __restrict__ incl,
                                                      const int* __restrict__ bpre,
                                                      int* __restrict__ offsets,
                                                      int* __restrict__ cursor) {
    int i = blockIdx.x * 1024 + threadIdx.x;
    if (i < N_NODES) {
        int inc = incl[i] + bpre[blockIdx.x];
        offsets[i + 1] = inc;
        cursor[i] = inc - counts[i];
    }
    if (i == 0) offsets[0] = 0;
}

// stores srcn DIRECTLY (self-loop: srcn = dst) -> aggregation needs no ei load, no branch
__global__ __launch_bounds__(256) void scatter_edges(const int* __restrict__ ei,
                                                     int* __restrict__ cursor,
                                                     int* __restrict__ csr) {
    int e = blockIdx.x * 256 + threadIdx.x;
    if (e < E_TOT) {
        int srcn, dst;
        if (e < E_EDGES) { srcn = ei[e]; dst = ei[E_EDGES + e]; }
        else             { srcn = dst = e - E_EDGES; }
        int pos = atomicAdd(&cursor[dst], 1);
        csr[pos] = srcn;
    }
}

// ---------------------------------------------------------------- GAT aggregation: wave per node, lane owns 8 channels
// No LDS, no barriers. csr holds srcn directly; 8 lanes of one head redundantly compute identical psum.
__global__ __launch_bounds__(256) void gat_aggregate4(const unsigned short* __restrict__ xtb,
                                                      const float* __restrict__ al_s,
                                                      const float* __restrict__ al_d,
                                                      const int* __restrict__ offsets,
                                                      const int* __restrict__ csr,
                                                      const float* __restrict__ bias,
                                                      unsigned short* __restrict__ outHi,
                                                      unsigned short* __restrict__ outLo) {
    const int lane = threadIdx.x & 63;
    const int n = blockIdx.x * 4 + (threadIdx.x >> 6);
    const int h = lane >> 3;            // head of this lane's channels
    const int c0 = lane * 8;            // channels c0..c0+7
    const int beg = offsets[n];
    const int deg = offsets[n + 1] - beg;
    const float aldv = al_d[n * HEADS + h];

    float acc[8] = {};
    float psum = 0.f;

#pragma unroll 4
    for (int i = 0; i < deg; ++i) {
        int srcn = csr[beg + i];                            // broadcast, src resolved
        float ev = al_s[srcn * HEADS + h] + aldv;
        ev = (ev >= 0.f) ? ev : 0.2f * ev;
        float p = __expf(ev);       // native v_exp; no max-subtraction: ev is O(1), fp32-safe
        psum += p;
        short8 row = *(const short8*)(xtb + (size_t)srcn * HID + c0);
#pragma unroll
        for (int j = 0; j < 8; ++j)
            acc[j] = fmaf(p, bf2f((unsigned short)row[j]), acc[j]);
    }

    const float inv = 1.f / (psum + 1e-16f);
    float4 b0 = *(const float4*)(bias + c0);
    float4 b1 = *(const float4*)(bias + c0 + 4);
    float bv[8] = { b0.x, b0.y, b0.z, b0.w, b1.x, b1.y, b1.z, b1.w };
    short8 h8, l8;
#pragma unroll
    for (int j = 0; j < 8; ++j) {
        float v = acc[j] * inv + bv[j];
        v = (v > 0.f) ? v : expm1f(v);      // ELU
        unsigned short hi = f2bf(v);
        h8[j] = (short)hi;
        l8[j] = (short)f2bf(v - bf2f(hi));
    }
    size_t o = (size_t)n * HID + c0;
    *(short8*)(outHi + o) = h8;
    *(short8*)(outLo + o) = l8;
}

// ---------------------------------------------------------------- pooling
__global__ __launch_bounds__(128) void find_bounds(const int* __restrict__ batch,
                                                   int* __restrict__ bounds) {
    int b = threadIdx.x;
    if (b <= B_GRAPHS) {
        int lo = 0, hi = N_NODES;
        while (lo < hi) {
            int mid = (lo + hi) >> 1;
            if (batch[mid] < b) lo = mid + 1; else hi = mid;
        }
        bounds[b] = lo;
    }
}

// stage A: grid (B_GRAPHS, 8 ch-blocks, 4 node-splits); 8 nodes in flight per block
__global__ __launch_bounds__(256) void pool_partial(const unsigned short* __restrict__ hHi,
                                                    const unsigned short* __restrict__ hLo,
                                                    const int* __restrict__ bounds,
                                                    float* __restrict__ partial) {
    const int b = blockIdx.x, y = blockIdx.y, k = blockIdx.z;
    const int s = bounds[b], cnt = bounds[b + 1] - s;
    const int ns = s + (cnt * k) / 4;
    const int ne = s + (cnt * (k + 1)) / 4;
    const int t = threadIdx.x;
    const int chp = t & 31;            // u32 pair within 64-ch block
    const int nl = t >> 5;             // 0..7

    float a0 = 0.f, a1 = 0.f;
    for (int n = ns + nl; n < ne; n += 8) {
        size_t off = (size_t)n * HID + y * 64 + chp * 2;
        unsigned vh = *(const unsigned*)(hHi + off);
        unsigned vl = *(const unsigned*)(hLo + off);
        a0 += bf2f((unsigned short)(vh & 0xffff)) + bf2f((unsigned short)(vl & 0xffff));
        a1 += bf2f((unsigned short)(vh >> 16)) + bf2f((unsigned short)(vl >> 16));
    }
    __shared__ float red[4][32][2];
    a0 += __shfl_xor(a0, 32);
    a1 += __shfl_xor(a1, 32);
    if ((t & 63) < 32) { red[t >> 6][chp][0] = a0; red[t >> 6][chp][1] = a1; }
    __syncthreads();
    if (t < 64) {
        int cp = t >> 1, c = t & 1;
        float v = red[0][cp][c] + red[1][cp][c] + red[2][cp][c] + red[3][cp][c];
        partial[(((size_t)k * B_GRAPHS + b) * 8 + y) * 64 + cp * 2 + c] = v;
    }
}

// stage B: grid B_GRAPHS x 512 threads
__global__ __launch_bounds__(512) void pool_final(const float* __restrict__ partial,
                                                  const int* __restrict__ bounds,
                                                  float* __restrict__ hG) {
    const int b = blockIdx.x, t = threadIdx.x;
    float v = 0.f;
#pragma unroll
    for (int k = 0; k < 4; ++k)
        v += partial[((size_t)k * B_GRAPHS + b) * HID + t];
    float cnt = fmaxf((float)(bounds[b + 1] - bounds[b]), 1.0f);
    hG[b * HID + t] = v / cnt;
}

// ---------------------------------------------------------------- classifier + softmax
__global__ __launch_bounds__(64) void classifier_kernel(const float* __restrict__ hG,
                                                        const float* __restrict__ Wl,
                                                        const float* __restrict__ bl,
                                                        float* __restrict__ outP) {
    int b = blockIdx.x;
    int tid = threadIdx.x;
    __shared__ float row[HID];
    __shared__ float logit[NCLS];
    for (int j = tid; j < HID; j += 64) row[j] = hG[b * HID + j];
    __syncthreads();
    if (tid < NCLS) {
        float acc = bl[tid];
        for (int j = 0; j < HID; ++j) acc += row[j] * Wl[j * NCLS + tid];
        logit[tid] = acc;
    }
    __syncthreads();
    if (tid == 0) {
        float mx = logit[0];
        for (int k = 1; k < NCLS; ++k) mx = fmaxf(mx, logit[k]);
        float ssum = 0.f, ex[NCLS];
        for (int k = 0; k < NCLS; ++k) { ex[k] = expf(logit[k] - mx); ssum += ex[k]; }
        for (int k = 0; k < NCLS; ++k) outP[b * NCLS + k] = ex[k] / ssum;
    }
}

// ---------------------------------------------------------------- launch
extern "C" void kernel_launch(void* const* d_in, const int* in_sizes, int n_in,
                              void* d_out, int out_size, void* d_ws, size_t ws_size,
                              hipStream_t stream) {
    const float* x     = (const float*)d_in[0];
    const int*   ei    = (const int*)d_in[1];
    const int*   batch = (const int*)d_in[2];
    const float* W[3]  = { (const float*)d_in[3], (const float*)d_in[7],  (const float*)d_in[11] };
    const float* as_[3] = { (const float*)d_in[4], (const float*)d_in[8],  (const float*)d_in[12] };
    const float* ad_[3] = { (const float*)d_in[5], (const float*)d_in[9],  (const float*)d_in[13] };
    const float* bb[3] = { (const float*)d_in[6], (const float*)d_in[10], (const float*)d_in[14] };
    const float* Wl    = (const float*)d_in[15];
    const float* bl    = (const float*)d_in[16];

    // workspace layout
    char* ws = (char*)d_ws;
    unsigned short* A1hi = (unsigned short*)ws;      ws += (size_t)M_PAD * F_INF * 2;  // 10.3 MB
    unsigned short* A1lo = (unsigned short*)ws;      ws += (size_t)M_PAD * F_INF * 2;
    unsigned short* A2hi = (unsigned short*)ws;      ws += (size_t)M_PAD * HID * 2;    // 20.6 MB
    unsigned short* A2lo = (unsigned short*)ws;      ws += (size_t)M_PAD * HID * 2;
    unsigned short* Bthi = (unsigned short*)ws;      ws += (size_t)HID * HID * 2;      // 0.5 MB
    unsigned short* Btlo = (unsigned short*)ws;      ws += (size_t)HID * HID * 2;
    unsigned short* xtb  = (unsigned short*)ws;      ws += (size_t)N_NODES * HID * 2;  // 20.5 MB
    float* als  = (float*)ws;                        ws += (size_t)N_NODES * HEADS * 4;
    float* ald  = (float*)ws;                        ws += (size_t)N_NODES * HEADS * 4;
    float* partial = (float*)ws;                     ws += (size_t)4 * B_GRAPHS * HID * 4; // 512 KB
    int* counts  = (int*)ws;                         ws += (size_t)N_NODES * 4;
    int* incl    = (int*)ws;                         ws += (size_t)N_NODES * 4;
    int* bsum    = (int*)ws;                         ws += 32 * 4;
    int* bpre    = (int*)ws;                         ws += 32 * 4;
    int* offsets = (int*)ws;                         ws += (size_t)(N_NODES + 1) * 4;
    int* cursor  = (int*)ws;                         ws += (size_t)N_NODES * 4;
    int* csr     = (int*)ws;                         ws += (size_t)E_TOT * 4;
    int* bounds  = (int*)ws;                         ws += (size_t)(B_GRAPHS + 1) * 4;

    float* hG = (float*)d_out;                 // 64*512
    float* probs = (float*)d_out + (size_t)B_GRAPHS * HID;

    // ---- CSR build (identical every call; rebuilt for determinism/no-caching)
    zero_ints<<<(N_NODES + 255) / 256, 256, 0, stream>>>(counts, N_NODES);
    count_edges<<<(E_TOT + 255) / 256, 256, 0, stream>>>(ei, counts);
    scan_local<<<NSCAN, 1024, 0, stream>>>(counts, incl, bsum);
    scan_bsums<<<1, 64, 0, stream>>>(bsum, bpre);
    scan_finalize<<<NSCAN, 1024, 0, stream>>>(counts, incl, bpre, offsets, cursor);
    scatter_edges<<<(E_TOT + 255) / 256, 256, 0, stream>>>(ei, cursor, csr);
    find_bounds<<<1, 128, 0, stream>>>(batch, bounds);
    zero_pad_rows<<<((M_PAD - N_NODES) * HID + 255) / 256, 256, 0, stream>>>(A2hi, A2lo);

    dim3 ggrid(M_PAD / 128, HID / 128);   // (157, 4)

    // ---- layer 1 (K = 256)
    {
        long totA = (long)M_PAD * F_INF;
        split_pad<<<(int)(totA / 4 / 256), 256, 0, stream>>>(x, A1hi, A1lo, N_NODES, F_INF, totA);
        transpose_split_B<<<dim3(HID / 32, F_INF / 32), 256, 0, stream>>>(W[0], Bthi, Btlo, F_INF);
        gemm_mfma<<<ggrid, 256, 0, stream>>>(A1hi, A1lo, Bthi, Btlo, as_[0], ad_[0],
                                             xtb, als, ald, N_NODES, F_INF);
        gat_aggregate4<<<N_NODES / 4, 256, 0, stream>>>(xtb, als, ald, offsets, csr, bb[0], A2hi, A2lo);
    }

    // ---- layers 2,3 (K = 512)
    for (int L = 1; L < 3; ++L) {
        transpose_split_B<<<dim3(HID / 32, HID / 32), 256, 0, stream>>>(W[L], Bthi, Btlo, HID);
        gemm_mfma<<<ggrid, 256, 0, stream>>>(A2hi, A2lo, Bthi, Btlo, as_[L], ad_[L],
                                             xtb, als, ald, N_NODES, HID);
        gat_aggregate4<<<N_NODES / 4, 256, 0, stream>>>(xtb, als, ald, offsets, csr, bb[L], A2hi, A2lo);
    }

    // ---- pool + classify
    {
        dim3 pgrid(B_GRAPHS, 8, 4);
        pool_partial<<<pgrid, 256, 0, stream>>>(A2hi, A2lo, bounds, partial);
        pool_final<<<B_GRAPHS, 512, 0, stream>>>(partial, bounds, hG);
    }
    classifier_kernel<<<B_GRAPHS, 64, 0, stream>>>(hG, Wl, bl, probs);
}

// Round 8
// 418.929 us; speedup vs baseline: 2.2365x; 1.0407x over previous
//
#include <hip/hip_runtime.h>
#include <hip/hip_bf16.h>
#include <math.h>

#define N_NODES  20000
#define E_EDGES  320000
#define E_TOT    (E_EDGES + N_NODES)
#define F_INF    256
#define HEADS    8
#define CDIM     64
#define HID      512
#define B_GRAPHS 64
#define NCLS     10
#define M_PAD    20096          // 157 * 128
#define NSCAN    20             // ceil(20000/1024)
#define NWG_GEMM 628            // 157 * 4

typedef __attribute__((ext_vector_type(8))) short short8;
typedef __attribute__((ext_vector_type(4))) float f32x4;

__device__ inline unsigned short f2bf(float x) {
    unsigned u = __builtin_bit_cast(unsigned, x);
    u += 0x7fff + ((u >> 16) & 1);          // round-to-nearest-even
    return (unsigned short)(u >> 16);
}
__device__ inline float bf2f(unsigned short h) {
    unsigned u = ((unsigned)h) << 16;
    return __builtin_bit_cast(float, u);
}

#define GLOAD_LDS16(g, l) __builtin_amdgcn_global_load_lds(                     \
        (const __attribute__((address_space(1))) void*)(g),                     \
        (__attribute__((address_space(3))) void*)(l), 16, 0, 0)

// ---------------------------------------------------------------- utils
__global__ __launch_bounds__(256) void zero_ints(int* p, int n) {
    int i = blockIdx.x * 256 + threadIdx.x;
    if (i < n) p[i] = 0;
}

__global__ __launch_bounds__(256) void zero_pad_rows(unsigned short* hi, unsigned short* lo) {
    int i = blockIdx.x * 256 + threadIdx.x;
    const int tot = (M_PAD - N_NODES) * HID;
    if (i < tot) {
        hi[(size_t)N_NODES * HID + i] = 0;
        lo[(size_t)N_NODES * HID + i] = 0;
    }
}

// ---------------------------------------------------------------- fp32 -> bf16 hi/lo split (row-padded)
__global__ __launch_bounds__(256) void split_pad(const float* __restrict__ src,
                                                 unsigned short* __restrict__ hi,
                                                 unsigned short* __restrict__ lo,
                                                 int M, int K, long total) {
    long i = ((long)blockIdx.x * 256 + threadIdx.x) * 4;
    if (i >= total) return;
    int row = (int)(i / K);
    float4 v = make_float4(0.f, 0.f, 0.f, 0.f);
    if (row < M) v = *(const float4*)(src + i);
    ushort4 h, l;
    h.x = f2bf(v.x); l.x = f2bf(v.x - bf2f(h.x));
    h.y = f2bf(v.y); l.y = f2bf(v.y - bf2f(h.y));
    h.z = f2bf(v.z); l.z = f2bf(v.z - bf2f(h.z));
    h.w = f2bf(v.w); l.w = f2bf(v.w - bf2f(h.w));
    *(ushort4*)(hi + i) = h;
    *(ushort4*)(lo + i) = l;
}

// ---------------------------------------------------------------- B[K][512] -> Bt_hi/lo[512][K]
__global__ __launch_bounds__(256) void transpose_split_B(const float* __restrict__ B,
                                                         unsigned short* __restrict__ Bthi,
                                                         unsigned short* __restrict__ Btlo,
                                                         int K) {
    __shared__ float t[32][33];
    int n0 = blockIdx.x * 32, k0 = blockIdx.y * 32;
    int tx = threadIdx.x & 31, ty = threadIdx.x >> 5;     // 32 x 8
    for (int i = ty; i < 32; i += 8) t[i][tx] = B[(size_t)(k0 + i) * HID + n0 + tx];
    __syncthreads();
    for (int i = ty; i < 32; i += 8) {
        float v = t[tx][i];                                // = B[k0+tx][n0+i]
        unsigned short h = f2bf(v);
        unsigned short l = f2bf(v - bf2f(h));
        Bthi[(size_t)(n0 + i) * K + k0 + tx] = h;
        Btlo[(size_t)(n0 + i) * K + k0 + tx] = l;
    }
}

// ---------------------------------------------------------------- bf16x3 MFMA GEMM, double-buffered pipeline
// LDS 16B-unit u holds (row=u>>2, kgrp=(u&3)^((row>>1)&3)): 2-way-max bank aliasing on ds_read_b128.
// 1-D grid with bijective XCD-chunked swizzle: 4 col-tiles of a row-panel run on one XCD (A L2-reuse).
__global__ __launch_bounds__(256) void gemm_mfma(const unsigned short* __restrict__ Ahi,
                                                 const unsigned short* __restrict__ Alo,
                                                 const unsigned short* __restrict__ Bhi,
                                                 const unsigned short* __restrict__ Blo,
                                                 const float* __restrict__ a_src,
                                                 const float* __restrict__ a_dst,
                                                 unsigned short* __restrict__ xtb,
                                                 float* __restrict__ al_s,
                                                 float* __restrict__ al_d,
                                                 int M, int K) {
    __shared__ short AsHi[2][4096], AsLo[2][4096], BsHi[2][4096], BsLo[2][4096]; // 64 KB
    const int tid = threadIdx.x;
    const int w = tid >> 6, lane = tid & 63;
    const int wr = w >> 1, wc = w & 1;

    // bijective XCD-chunked swizzle (m204): nwg=628, q=78, r=4
    const int xcd = blockIdx.x & 7, idx = blockIdx.x >> 3;
    const int q = NWG_GEMM >> 3, r = NWG_GEMM & 7;
    const int wg = (xcd < r) ? (xcd * (q + 1) + idx) : (r * (q + 1) + (xcd - r) * q + idx);
    const int row0 = (wg >> 2) * 128, col0 = (wg & 3) * 128;

    long offA[2], offB[2];
    int ldsU[2];
#pragma unroll
    for (int i = 0; i < 2; ++i) {
        int u = w * 128 + i * 64 + lane;
        int row = u >> 2;
        int kg = (u & 3) ^ ((row >> 1) & 3);               // inverse of read swizzle
        offA[i] = ((long)(row0 + row) * K + kg * 8) * 2;   // bytes
        offB[i] = ((long)(col0 + row) * K + kg * 8) * 2;
        ldsU[i] = (w * 128 + i * 64) * 8;                  // short index of LDS base
    }

    const int r16 = lane & 15, kg = lane >> 4;
    int aOff[4], bOff[4];
#pragma unroll
    for (int i = 0; i < 4; ++i) {
        int row = wr * 64 + i * 16 + r16;
        aOff[i] = (row * 4 + (kg ^ ((row >> 1) & 3))) * 16;   // slots cover all 8 banks-groups/8 rows
        int col = wc * 64 + i * 16 + r16;
        bOff[i] = (col * 4 + (kg ^ ((col >> 1) & 3))) * 16;
    }

    const char* pAhi = (const char*)Ahi;
    const char* pAlo = (const char*)Alo;
    const char* pBhi = (const char*)Bhi;
    const char* pBlo = (const char*)Blo;

    f32x4 acc[4][4] = {};

#define STAGE(buf, kk) do {                                                      \
        long kb = (long)(kk) * 64;                                               \
        _Pragma("unroll")                                                        \
        for (int i_ = 0; i_ < 2; ++i_) {                                         \
            GLOAD_LDS16(pAhi + offA[i_] + kb, &AsHi[buf][ldsU[i_]]);             \
            GLOAD_LDS16(pAlo + offA[i_] + kb, &AsLo[buf][ldsU[i_]]);             \
            GLOAD_LDS16(pBhi + offB[i_] + kb, &BsHi[buf][ldsU[i_]]);             \
            GLOAD_LDS16(pBlo + offB[i_] + kb, &BsLo[buf][ldsU[i_]]);             \
        }                                                                        \
    } while (0)

#define COMPUTE(buf) do {                                                        \
        short8 fah[4], fal[4], fbh[4], fbl[4];                                   \
        _Pragma("unroll")                                                        \
        for (int i_ = 0; i_ < 4; ++i_) {                                         \
            fah[i_] = *(const short8*)((const char*)AsHi[buf] + aOff[i_]);       \
            fal[i_] = *(const short8*)((const char*)AsLo[buf] + aOff[i_]);       \
            fbh[i_] = *(const short8*)((const char*)BsHi[buf] + bOff[i_]);       \
            fbl[i_] = *(const short8*)((const char*)BsLo[buf] + bOff[i_]);       \
        }                                                                        \
        _Pragma("unroll")                                                        \
        for (int i_ = 0; i_ < 4; ++i_)                                           \
            _Pragma("unroll")                                                    \
            for (int j_ = 0; j_ < 4; ++j_) {                                     \
                acc[i_][j_] = __builtin_amdgcn_mfma_f32_16x16x32_bf16(fah[i_], fbh[j_], acc[i_][j_], 0, 0, 0); \
                acc[i_][j_] = __builtin_amdgcn_mfma_f32_16x16x32_bf16(fah[i_], fbl[j_], acc[i_][j_], 0, 0, 0); \
                acc[i_][j_] = __builtin_amdgcn_mfma_f32_16x16x32_bf16(fal[i_], fbh[j_], acc[i_][j_], 0, 0, 0); \
            }                                                                    \
    } while (0)

    const int NS = K >> 5;
    STAGE(0, 0);
    asm volatile("s_waitcnt vmcnt(0)" ::: "memory");
    __builtin_amdgcn_s_barrier();
    int cur = 0;
    for (int t = 0; t < NS - 1; ++t) {
        STAGE(cur ^ 1, t + 1);          // issue next tile BEFORE compute -> latency hides under MFMA
        COMPUTE(cur);
        asm volatile("s_waitcnt vmcnt(0)" ::: "memory");   // next tile landed (overlapped)
        __builtin_amdgcn_s_barrier();
        cur ^= 1;
    }
    COMPUTE(cur);                        // epilogue tile, no prefetch

#undef STAGE
#undef COMPUTE

    // ---- epilogue. C/D layout: col=lane&15 within 16-block, row=(lane>>4)*4+r.
    // This wave's 64 cols = head h's channel block.
    const int h = (col0 >> 6) + wc;
    float asv[4], adv[4];
#pragma unroll
    for (int j = 0; j < 4; ++j) {
        asv[j] = a_src[h * CDIM + j * 16 + r16];
        adv[j] = a_dst[h * CDIM + j * 16 + r16];
    }
#pragma unroll
    for (int i = 0; i < 4; ++i) {
        int rbase = row0 + wr * 64 + i * 16 + (lane >> 4) * 4;
        // al_s / al_d: dot over the 64 channels of head h (4 j-blocks x 16 lanes)
#pragma unroll
        for (int rr = 0; rr < 4; ++rr) {
            float ss = acc[i][0][rr] * asv[0] + acc[i][1][rr] * asv[1]
                     + acc[i][2][rr] * asv[2] + acc[i][3][rr] * asv[3];
            float dd = acc[i][0][rr] * adv[0] + acc[i][1][rr] * adv[1]
                     + acc[i][2][rr] * adv[2] + acc[i][3][rr] * adv[3];
#pragma unroll
            for (int off = 1; off < 16; off <<= 1) {
                ss += __shfl_xor(ss, off);
                dd += __shfl_xor(dd, off);
            }
            int row = rbase + rr;
            if ((lane & 15) == 0 && row < M) {
                al_s[row * HEADS + h] = ss;
                al_d[row * HEADS + h] = dd;
            }
        }
        // xtb bf16 store
#pragma unroll
        for (int j = 0; j < 4; ++j) {
            int col = col0 + wc * 64 + j * 16 + r16;
#pragma unroll
            for (int rr = 0; rr < 4; ++rr)
                if (rbase + rr < M) xtb[(size_t)(rbase + rr) * HID + col] = f2bf(acc[i][j][rr]);
        }
    }
}

// ---------------------------------------------------------------- CSR build
__global__ __launch_bounds__(256) void count_edges(const int* __restrict__ ei,
                                                   int* __restrict__ counts) {
    int e = blockIdx.x * 256 + threadIdx.x;
    if (e < E_TOT) {
        int dst = (e < E_EDGES) ? ei[E_EDGES + e] : (e - E_EDGES);
        atomicAdd(&counts[dst], 1);
    }
}

// parallel 3-phase scan
__global__ __launch_bounds__(1024) void scan_local(const int* __restrict__ counts,
                                                   int* __restrict__ incl,
                                                   int* __restrict__ bsum) {
    __shared__ int s[1024];
    int tid = threadIdx.x;
    int i = blockIdx.x * 1024 + tid;
    int v = (i < N_NODES) ? counts[i] : 0;
    s[tid] = v;
    __syncthreads();
    for (int off = 1; off < 1024; off <<= 1) {
        int t = (tid >= off) ? s[tid - off] : 0;
        __syncthreads();
        s[tid] += t;
        __syncthreads();
    }
    if (i < N_NODES) incl[i] = s[tid];
    if (tid == 1023) bsum[blockIdx.x] = s[1023];
}

__global__ __launch_bounds__(64) void scan_bsums(const int* __restrict__ bsum,
                                                 int* __restrict__ bpre) {
    int lane = threadIdx.x;
    int v = (lane < NSCAN) ? bsum[lane] : 0;
    int incl = v;
#pragma unroll
    for (int off = 1; off < 32; off <<= 1) {
        int t = __shfl_up(incl, off);
        if (lane >= off) incl += t;
    }
    if (lane < NSCAN) bpre[lane] = incl - v;
}

__global__ __launch_bounds__(1024) void scan_finalize(const int* __restrict__ counts,
                                                      const int* __restrict__ incl,
                                                      const int* __restrict__ bpre,
                                                      int* __restrict__ offsets,
                                                      int* __restrict__ cursor) {
    int i = blockIdx.x * 1024 + threadIdx.x;
    if (i < N_NODES) {
        int inc = incl[i] + bpre[blockIdx.x];
        offsets[i + 1] = inc;
        cursor[i] = inc - counts[i];
    }
    if (i == 0) offsets[0] = 0;
}

// stores srcn DIRECTLY (self-loop: srcn = dst) -> aggregation needs no ei load, no branch
__global__ __launch_bounds__(256) void scatter_edges(const int* __restrict__ ei,
                                                     int* __restrict__ cursor,
                                                     int* __restrict__ csr) {
    int e = blockIdx.x * 256 + threadIdx.x;
    if (e < E_TOT) {
        int srcn, dst;
        if (e < E_EDGES) { srcn = ei[e]; dst = ei[E_EDGES + e]; }
        else             { srcn = dst = e - E_EDGES; }
        int pos = atomicAdd(&cursor[dst], 1);
        csr[pos] = srcn;
    }
}

// ---------------------------------------------------------------- GAT aggregation: wave per node, lane owns 8 channels
// No LDS, no barriers. csr holds srcn directly; 8 lanes of one head redundantly compute identical psum.
__global__ __launch_bounds__(256) void gat_aggregate4(const unsigned short* __restrict__ xtb,
                                                      const float* __restrict__ al_s,
                                                      const float* __restrict__ al_d,
                                                      const int* __restrict__ offsets,
                                                      const int* __restrict__ csr,
                                                      const float* __restrict__ bias,
                                                      unsigned short* __restrict__ outHi,
                                                      unsigned short* __restrict__ outLo) {
    const int lane = threadIdx.x & 63;
    const int n = blockIdx.x * 4 + (threadIdx.x >> 6);
    const int h = lane >> 3;            // head of this lane's channels
    const int c0 = lane * 8;            // channels c0..c0+7
    const int beg = offsets[n];
    const int deg = offsets[n + 1] - beg;
    const float aldv = al_d[n * HEADS + h];

    float acc[8] = {};
    float psum = 0.f;

#pragma unroll 4
    for (int i = 0; i < deg; ++i) {
        int srcn = csr[beg + i];                            // broadcast, src resolved
        float ev = al_s[srcn * HEADS + h] + aldv;
        ev = (ev >= 0.f) ? ev : 0.2f * ev;
        float p = __expf(ev);       // native v_exp; no max-subtraction: ev is O(1), fp32-safe
        psum += p;
        short8 row = *(const short8*)(xtb + (size_t)srcn * HID + c0);
#pragma unroll
        for (int j = 0; j < 8; ++j)
            acc[j] = fmaf(p, bf2f((unsigned short)row[j]), acc[j]);
    }

    const float inv = 1.f / (psum + 1e-16f);
    float4 b0 = *(const float4*)(bias + c0);
    float4 b1 = *(const float4*)(bias + c0 + 4);
    float bv[8] = { b0.x, b0.y, b0.z, b0.w, b1.x, b1.y, b1.z, b1.w };
    short8 h8, l8;
#pragma unroll
    for (int j = 0; j < 8; ++j) {
        float v = acc[j] * inv + bv[j];
        v = (v > 0.f) ? v : expm1f(v);      // ELU
        unsigned short hi = f2bf(v);
        h8[j] = (short)hi;
        l8[j] = (short)f2bf(v - bf2f(hi));
    }
    size_t o = (size_t)n * HID + c0;
    *(short8*)(outHi + o) = h8;
    *(short8*)(outLo + o) = l8;
}

// ---------------------------------------------------------------- pooling
__global__ __launch_bounds__(128) void find_bounds(const int* __restrict__ batch,
                                                   int* __restrict__ bounds) {
    int b = threadIdx.x;
    if (b <= B_GRAPHS) {
        int lo = 0, hi = N_NODES;
        while (lo < hi) {
            int mid = (lo + hi) >> 1;
            if (batch[mid] < b) lo = mid + 1; else hi = mid;
        }
        bounds[b] = lo;
    }
}

// stage A: grid (B_GRAPHS, 8 ch-blocks, 4 node-splits); 8 nodes in flight per block
__global__ __launch_bounds__(256) void pool_partial(const unsigned short* __restrict__ hHi,
                                                    const unsigned short* __restrict__ hLo,
                                                    const int* __restrict__ bounds,
                                                    float* __restrict__ partial) {
    const int b = blockIdx.x, y = blockIdx.y, k = blockIdx.z;
    const int s = bounds[b], cnt = bounds[b + 1] - s;
    const int ns = s + (cnt * k) / 4;
    const int ne = s + (cnt * (k + 1)) / 4;
    const int t = threadIdx.x;
    const int chp = t & 31;            // u32 pair within 64-ch block
    const int nl = t >> 5;             // 0..7

    float a0 = 0.f, a1 = 0.f;
    for (int n = ns + nl; n < ne; n += 8) {
        size_t off = (size_t)n * HID + y * 64 + chp * 2;
        unsigned vh = *(const unsigned*)(hHi + off);
        unsigned vl = *(const unsigned*)(hLo + off);
        a0 += bf2f((unsigned short)(vh & 0xffff)) + bf2f((unsigned short)(vl & 0xffff));
        a1 += bf2f((unsigned short)(vh >> 16)) + bf2f((unsigned short)(vl >> 16));
    }
    __shared__ float red[4][32][2];
    a0 += __shfl_xor(a0, 32);
    a1 += __shfl_xor(a1, 32);
    if ((t & 63) < 32) { red[t >> 6][chp][0] = a0; red[t >> 6][chp][1] = a1; }
    __syncthreads();
    if (t < 64) {
        int cp = t >> 1, c = t & 1;
        float v = red[0][cp][c] + red[1][cp][c] + red[2][cp][c] + red[3][cp][c];
        partial[(((size_t)k * B_GRAPHS + b) * 8 + y) * 64 + cp * 2 + c] = v;
    }
}

// stage B: grid B_GRAPHS x 512 threads
__global__ __launch_bounds__(512) void pool_final(const float* __restrict__ partial,
                                                  const int* __restrict__ bounds,
                                                  float* __restrict__ hG) {
    const int b = blockIdx.x, t = threadIdx.x;
    float v = 0.f;
#pragma unroll
    for (int k = 0; k < 4; ++k)
        v += partial[((size_t)k * B_GRAPHS + b) * HID + t];
    float cnt = fmaxf((float)(bounds[b + 1] - bounds[b]), 1.0f);
    hG[b * HID + t] = v / cnt;
}

// ---------------------------------------------------------------- classifier + softmax
__global__ __launch_bounds__(64) void classifier_kernel(const float* __restrict__ hG,
                                                        const float* __restrict__ Wl,
                                                        const float* __restrict__ bl,
                                                        float* __restrict__ outP) {
    int b = blockIdx.x;
    int tid = threadIdx.x;
    __shared__ float row[HID];
    __shared__ float logit[NCLS];
    for (int j = tid; j < HID; j += 64) row[j] = hG[b * HID + j];
    __syncthreads();
    if (tid < NCLS) {
        float acc = bl[tid];
        for (int j = 0; j < HID; ++j) acc += row[j] * Wl[j * NCLS + tid];
        logit[tid] = acc;
    }
    __syncthreads();
    if (tid == 0) {
        float mx = logit[0];
        for (int k = 1; k < NCLS; ++k) mx = fmaxf(mx, logit[k]);
        float ssum = 0.f, ex[NCLS];
        for (int k = 0; k < NCLS; ++k) { ex[k] = expf(logit[k] - mx); ssum += ex[k]; }
        for (int k = 0; k < NCLS; ++k) outP[b * NCLS + k] = ex[k] / ssum;
    }
}

// ---------------------------------------------------------------- launch
extern "C" void kernel_launch(void* const* d_in, const int* in_sizes, int n_in,
                              void* d_out, int out_size, void* d_ws, size_t ws_size,
                              hipStream_t stream) {
    const float* x     = (const float*)d_in[0];
    const int*   ei    = (const int*)d_in[1];
    const int*   batch = (const int*)d_in[2];
    const float* W[3]  = { (const float*)d_in[3], (const float*)d_in[7],  (const float*)d_in[11] };
    const float* as_[3] = { (const float*)d_in[4], (const float*)d_in[8],  (const float*)d_in[12] };
    const float* ad_[3] = { (const float*)d_in[5], (const float*)d_in[9],  (const float*)d_in[13] };
    const float* bb[3] = { (const float*)d_in[6], (const float*)d_in[10], (const float*)d_in[14] };
    const float* Wl    = (const float*)d_in[15];
    const float* bl    = (const float*)d_in[16];

    // workspace layout
    char* ws = (char*)d_ws;
    unsigned short* A1hi = (unsigned short*)ws;      ws += (size_t)M_PAD * F_INF * 2;  // 10.3 MB
    unsigned short* A1lo = (unsigned short*)ws;      ws += (size_t)M_PAD * F_INF * 2;
    unsigned short* A2hi = (unsigned short*)ws;      ws += (size_t)M_PAD * HID * 2;    // 20.6 MB
    unsigned short* A2lo = (unsigned short*)ws;      ws += (size_t)M_PAD * HID * 2;
    unsigned short* Bthi = (unsigned short*)ws;      ws += (size_t)HID * HID * 2;      // 0.5 MB
    unsigned short* Btlo = (unsigned short*)ws;      ws += (size_t)HID * HID * 2;
    unsigned short* xtb  = (unsigned short*)ws;      ws += (size_t)N_NODES * HID * 2;  // 20.5 MB
    float* als  = (float*)ws;                        ws += (size_t)N_NODES * HEADS * 4;
    float* ald  = (float*)ws;                        ws += (size_t)N_NODES * HEADS * 4;
    float* partial = (float*)ws;                     ws += (size_t)4 * B_GRAPHS * HID * 4; // 512 KB
    int* counts  = (int*)ws;                         ws += (size_t)N_NODES * 4;
    int* incl    = (int*)ws;                         ws += (size_t)N_NODES * 4;
    int* bsum    = (int*)ws;                         ws += 32 * 4;
    int* bpre    = (int*)ws;                         ws += 32 * 4;
    int* offsets = (int*)ws;                         ws += (size_t)(N_NODES + 1) * 4;
    int* cursor  = (int*)ws;                         ws += (size_t)N_NODES * 4;
    int* csr     = (int*)ws;                         ws += (size_t)E_TOT * 4;
    int* bounds  = (int*)ws;                         ws += (size_t)(B_GRAPHS + 1) * 4;

    float* hG = (float*)d_out;                 // 64*512
    float* probs = (float*)d_out + (size_t)B_GRAPHS * HID;

    // ---- CSR build (identical every call; rebuilt for determinism/no-caching)
    zero_ints<<<(N_NODES + 255) / 256, 256, 0, stream>>>(counts, N_NODES);
    count_edges<<<(E_TOT + 255) / 256, 256, 0, stream>>>(ei, counts);
    scan_local<<<NSCAN, 1024, 0, stream>>>(counts, incl, bsum);
    scan_bsums<<<1, 64, 0, stream>>>(bsum, bpre);
    scan_finalize<<<NSCAN, 1024, 0, stream>>>(counts, incl, bpre, offsets, cursor);
    scatter_edges<<<(E_TOT + 255) / 256, 256, 0, stream>>>(ei, cursor, csr);
    find_bounds<<<1, 128, 0, stream>>>(batch, bounds);
    zero_pad_rows<<<((M_PAD - N_NODES) * HID + 255) / 256, 256, 0, stream>>>(A2hi, A2lo);

    // ---- layer 1 (K = 256)
    {
        long totA = (long)M_PAD * F_INF;
        split_pad<<<(int)(totA / 4 / 256), 256, 0, stream>>>(x, A1hi, A1lo, N_NODES, F_INF, totA);
        transpose_split_B<<<dim3(HID / 32, F_INF / 32), 256, 0, stream>>>(W[0], Bthi, Btlo, F_INF);
        gemm_mfma<<<NWG_GEMM, 256, 0, stream>>>(A1hi, A1lo, Bthi, Btlo, as_[0], ad_[0],
                                                xtb, als, ald, N_NODES, F_INF);
        gat_aggregate4<<<N_NODES / 4, 256, 0, stream>>>(xtb, als, ald, offsets, csr, bb[0], A2hi, A2lo);
    }

    // ---- layers 2,3 (K = 512)
    for (int L = 1; L < 3; ++L) {
        transpose_split_B<<<dim3(HID / 32, HID / 32), 256, 0, stream>>>(W[L], Bthi, Btlo, HID);
        gemm_mfma<<<NWG_GEMM, 256, 0, stream>>>(A2hi, A2lo, Bthi, Btlo, as_[L], ad_[L],
                                                xtb, als, ald, N_NODES, HID);
        gat_aggregate4<<<N_NODES / 4, 256, 0, stream>>>(xtb, als, ald, offsets, csr, bb[L], A2hi, A2lo);
    }

    // ---- pool + classify
    {
        dim3 pgrid(B_GRAPHS, 8, 4);
        pool_partial<<<pgrid, 256, 0, stream>>>(A2hi, A2lo, bounds, partial);
        pool_final<<<B_GRAPHS, 512, 0, stream>>>(partial, bounds, hG);
    }
    classifier_kernel<<<B_GRAPHS, 64, 0, stream>>>(hG, Wl, bl, probs);
}

// Round 9
// 405.326 us; speedup vs baseline: 2.3116x; 1.0336x over previous
//
#include <hip/hip_runtime.h>
#include <hip/hip_bf16.h>
#include <math.h>

#define N_NODES  20000
#define E_EDGES  320000
#define E_TOT    (E_EDGES + N_NODES)
#define F_INF    256
#define HEADS    8
#define CDIM     64
#define HID      512
#define B_GRAPHS 64
#define NCLS     10
#define M_PAD    20096          // 157 * 128
#define NSCAN    20             // ceil(20000/1024)
#define NWG_GEMM 628            // 157 * 4

typedef __attribute__((ext_vector_type(8))) short short8;
typedef __attribute__((ext_vector_type(4))) float f32x4;

__device__ inline unsigned short f2bf(float x) {
    unsigned u = __builtin_bit_cast(unsigned, x);
    u += 0x7fff + ((u >> 16) & 1);          // round-to-nearest-even
    return (unsigned short)(u >> 16);
}
__device__ inline float bf2f(unsigned short h) {
    unsigned u = ((unsigned)h) << 16;
    return __builtin_bit_cast(float, u);
}

#define GLOAD_LDS16(g, l) __builtin_amdgcn_global_load_lds(                     \
        (const __attribute__((address_space(1))) void*)(g),                     \
        (__attribute__((address_space(3))) void*)(l), 16, 0, 0)

// ---------------------------------------------------------------- utils
__global__ __launch_bounds__(256) void zero_ints(int* p, int n) {
    int i = blockIdx.x * 256 + threadIdx.x;
    if (i < n) p[i] = 0;
}

__global__ __launch_bounds__(256) void zero_pad_rows(unsigned short* hi, unsigned short* lo) {
    int i = blockIdx.x * 256 + threadIdx.x;
    const int tot = (M_PAD - N_NODES) * HID;
    if (i < tot) {
        hi[(size_t)N_NODES * HID + i] = 0;
        lo[(size_t)N_NODES * HID + i] = 0;
    }
}

// ---------------------------------------------------------------- fp32 -> bf16 hi/lo split (row-padded)
__global__ __launch_bounds__(256) void split_pad(const float* __restrict__ src,
                                                 unsigned short* __restrict__ hi,
                                                 unsigned short* __restrict__ lo,
                                                 int M, int K, long total) {
    long i = ((long)blockIdx.x * 256 + threadIdx.x) * 4;
    if (i >= total) return;
    int row = (int)(i / K);
    float4 v = make_float4(0.f, 0.f, 0.f, 0.f);
    if (row < M) v = *(const float4*)(src + i);
    ushort4 h, l;
    h.x = f2bf(v.x); l.x = f2bf(v.x - bf2f(h.x));
    h.y = f2bf(v.y); l.y = f2bf(v.y - bf2f(h.y));
    h.z = f2bf(v.z); l.z = f2bf(v.z - bf2f(h.z));
    h.w = f2bf(v.w); l.w = f2bf(v.w - bf2f(h.w));
    *(ushort4*)(hi + i) = h;
    *(ushort4*)(lo + i) = l;
}

// ---------------------------------------------------------------- B[K][512] -> Bt_hi/lo[512][K]
__global__ __launch_bounds__(256) void transpose_split_B(const float* __restrict__ B,
                                                         unsigned short* __restrict__ Bthi,
                                                         unsigned short* __restrict__ Btlo,
                                                         int K) {
    __shared__ float t[32][33];
    int n0 = blockIdx.x * 32, k0 = blockIdx.y * 32;
    int tx = threadIdx.x & 31, ty = threadIdx.x >> 5;     // 32 x 8
    for (int i = ty; i < 32; i += 8) t[i][tx] = B[(size_t)(k0 + i) * HID + n0 + tx];
    __syncthreads();
    for (int i = ty; i < 32; i += 8) {
        float v = t[tx][i];                                // = B[k0+tx][n0+i]
        unsigned short h = f2bf(v);
        unsigned short l = f2bf(v - bf2f(h));
        Bthi[(size_t)(n0 + i) * K + k0 + tx] = h;
        Btlo[(size_t)(n0 + i) * K + k0 + tx] = l;
    }
}

// ---------------------------------------------------------------- bf16x3 MFMA GEMM, m97 structure:
// single 32KB buffer, 2 barriers/K-step, ~5 blocks/CU -> cross-block TLP hides the staging drain.
// LDS 16B-unit u holds (row=u>>2, kgrp=(u&3)^((row>>1)&3)): 2-way-max bank aliasing on ds_read_b128.
// 1-D grid with bijective XCD-chunked swizzle: 4 col-tiles of a row-panel run on one XCD (A L2-reuse).
__global__ __launch_bounds__(256) void gemm_mfma(const unsigned short* __restrict__ Ahi,
                                                 const unsigned short* __restrict__ Alo,
                                                 const unsigned short* __restrict__ Bhi,
                                                 const unsigned short* __restrict__ Blo,
                                                 const float* __restrict__ a_src,
                                                 const float* __restrict__ a_dst,
                                                 unsigned short* __restrict__ xtb,
                                                 float* __restrict__ al_s,
                                                 float* __restrict__ al_d,
                                                 int M, int K) {
    __shared__ short AsHi[4096], AsLo[4096], BsHi[4096], BsLo[4096];   // 32 KB
    const int tid = threadIdx.x;
    const int w = tid >> 6, lane = tid & 63;
    const int wr = w >> 1, wc = w & 1;

    // bijective XCD-chunked swizzle (m204): nwg=628, q=78, r=4
    const int xcd = blockIdx.x & 7, idx = blockIdx.x >> 3;
    const int q = NWG_GEMM >> 3, r = NWG_GEMM & 7;
    const int wg = (xcd < r) ? (xcd * (q + 1) + idx) : (r * (q + 1) + (xcd - r) * q + idx);
    const int row0 = (wg >> 2) * 128, col0 = (wg & 3) * 128;

    long offA[2], offB[2];
    int ldsU[2];
#pragma unroll
    for (int i = 0; i < 2; ++i) {
        int u = w * 128 + i * 64 + lane;
        int row = u >> 2;
        int kg = (u & 3) ^ ((row >> 1) & 3);               // inverse of read swizzle
        offA[i] = ((long)(row0 + row) * K + kg * 8) * 2;   // bytes
        offB[i] = ((long)(col0 + row) * K + kg * 8) * 2;
        ldsU[i] = (w * 128 + i * 64) * 8;                  // short index of LDS base
    }

    const int r16 = lane & 15, kg = lane >> 4;
    int aOff[4], bOff[4];
#pragma unroll
    for (int i = 0; i < 4; ++i) {
        int row = wr * 64 + i * 16 + r16;
        aOff[i] = (row * 4 + (kg ^ ((row >> 1) & 3))) * 16;   // slots cover all 8 positions per 8 rows
        int col = wc * 64 + i * 16 + r16;
        bOff[i] = (col * 4 + (kg ^ ((col >> 1) & 3))) * 16;
    }

    const char* pAhi = (const char*)Ahi;
    const char* pAlo = (const char*)Alo;
    const char* pBhi = (const char*)Bhi;
    const char* pBlo = (const char*)Blo;

    f32x4 acc[4][4] = {};

    for (int kk = 0; kk < K; kk += 32) {
        long kb = (long)kk * 2;
        __syncthreads();                 // previous step's ds_reads done
#pragma unroll
        for (int i = 0; i < 2; ++i) {
            GLOAD_LDS16(pAhi + offA[i] + kb, AsHi + ldsU[i]);
            GLOAD_LDS16(pAlo + offA[i] + kb, AsLo + ldsU[i]);
            GLOAD_LDS16(pBhi + offB[i] + kb, BsHi + ldsU[i]);
            GLOAD_LDS16(pBlo + offB[i] + kb, BsLo + ldsU[i]);
        }
        __syncthreads();                 // drains vmcnt; other resident blocks run through this

        short8 fah[4], fal[4], fbh[4], fbl[4];
#pragma unroll
        for (int i = 0; i < 4; ++i) {
            fah[i] = *(const short8*)((const char*)AsHi + aOff[i]);
            fal[i] = *(const short8*)((const char*)AsLo + aOff[i]);
            fbh[i] = *(const short8*)((const char*)BsHi + bOff[i]);
            fbl[i] = *(const short8*)((const char*)BsLo + bOff[i]);
        }
#pragma unroll
        for (int i = 0; i < 4; ++i)
#pragma unroll
            for (int j = 0; j < 4; ++j) {
                acc[i][j] = __builtin_amdgcn_mfma_f32_16x16x32_bf16(fah[i], fbh[j], acc[i][j], 0, 0, 0);
                acc[i][j] = __builtin_amdgcn_mfma_f32_16x16x32_bf16(fah[i], fbl[j], acc[i][j], 0, 0, 0);
                acc[i][j] = __builtin_amdgcn_mfma_f32_16x16x32_bf16(fal[i], fbh[j], acc[i][j], 0, 0, 0);
            }
    }

    // ---- epilogue. C/D layout: col=lane&15 within 16-block, row=(lane>>4)*4+r.
    // This wave's 64 cols = head h's channel block.
    const int h = (col0 >> 6) + wc;
    float asv[4], adv[4];
#pragma unroll
    for (int j = 0; j < 4; ++j) {
        asv[j] = a_src[h * CDIM + j * 16 + r16];
        adv[j] = a_dst[h * CDIM + j * 16 + r16];
    }
#pragma unroll
    for (int i = 0; i < 4; ++i) {
        int rbase = row0 + wr * 64 + i * 16 + (lane >> 4) * 4;
        // al_s / al_d: dot over the 64 channels of head h (4 j-blocks x 16 lanes)
#pragma unroll
        for (int rr = 0; rr < 4; ++rr) {
            float ss = acc[i][0][rr] * asv[0] + acc[i][1][rr] * asv[1]
                     + acc[i][2][rr] * asv[2] + acc[i][3][rr] * asv[3];
            float dd = acc[i][0][rr] * adv[0] + acc[i][1][rr] * adv[1]
                     + acc[i][2][rr] * adv[2] + acc[i][3][rr] * adv[3];
#pragma unroll
            for (int off = 1; off < 16; off <<= 1) {
                ss += __shfl_xor(ss, off);
                dd += __shfl_xor(dd, off);
            }
            int row = rbase + rr;
            if ((lane & 15) == 0 && row < M) {
                al_s[row * HEADS + h] = ss;
                al_d[row * HEADS + h] = dd;
            }
        }
        // xtb bf16 store
#pragma unroll
        for (int j = 0; j < 4; ++j) {
            int col = col0 + wc * 64 + j * 16 + r16;
#pragma unroll
            for (int rr = 0; rr < 4; ++rr)
                if (rbase + rr < M) xtb[(size_t)(rbase + rr) * HID + col] = f2bf(acc[i][j][rr]);
        }
    }
}

// ---------------------------------------------------------------- CSR build
__global__ __launch_bounds__(256) void count_edges(const int* __restrict__ ei,
                                                   int* __restrict__ counts) {
    int e = blockIdx.x * 256 + threadIdx.x;
    if (e < E_TOT) {
        int dst = (e < E_EDGES) ? ei[E_EDGES + e] : (e - E_EDGES);
        atomicAdd(&counts[dst], 1);
    }
}

// parallel 3-phase scan
__global__ __launch_bounds__(1024) void scan_local(const int* __restrict__ counts,
                                                   int* __restrict__ incl,
                                                   int* __restrict__ bsum) {
    __shared__ int s[1024];
    int tid = threadIdx.x;
    int i = blockIdx.x * 1024 + tid;
    int v = (i < N_NODES) ? counts[i] : 0;
    s[tid] = v;
    __syncthreads();
    for (int off = 1; off < 1024; off <<= 1) {
        int t = (tid >= off) ? s[tid - off] : 0;
        __syncthreads();
        s[tid] += t;
        __syncthreads();
    }
    if (i < N_NODES) incl[i] = s[tid];
    if (tid == 1023) bsum[blockIdx.x] = s[1023];
}

__global__ __launch_bounds__(64) void scan_bsums(const int* __restrict__ bsum,
                                                 int* __restrict__ bpre) {
    int lane = threadIdx.x;
    int v = (lane < NSCAN) ? bsum[lane] : 0;
    int incl = v;
#pragma unroll
    for (int off = 1; off < 32; off <<= 1) {
        int t = __shfl_up(incl, off);
        if (lane >= off) incl += t;
    }
    if (lane < NSCAN) bpre[lane] = incl - v;
}

__global__ __launch_bounds__(1024) void scan_finalize(const int* __restrict__ counts,
                                                      const int* __restrict__ incl,
                                                      const int* __restrict__ bpre,
                                                      int* __restrict__ offsets,
                                                      int* __restrict__ cursor) {
    int i = blockIdx.x * 1024 + threadIdx.x;
    if (i < N_NODES) {
        int inc = incl[i] + bpre[blockIdx.x];
        offsets[i + 1] = inc;
        cursor[i] = inc - counts[i];
    }
    if (i == 0) offsets[0] = 0;
}

// stores srcn DIRECTLY (self-loop: srcn = dst) -> aggregation needs no ei load, no branch
__global__ __launch_bounds__(256) void scatter_edges(const int* __restrict__ ei,
                                                     int* __restrict__ cursor,
                                                     int* __restrict__ csr) {
    int e = blockIdx.x * 256 + threadIdx.x;
    if (e < E_TOT) {
        int srcn, dst;
        if (e < E_EDGES) { srcn = ei[e]; dst = ei[E_EDGES + e]; }
        else             { srcn = dst = e - E_EDGES; }
        int pos = atomicAdd(&cursor[dst], 1);
        csr[pos] = srcn;
    }
}

// ---------------------------------------------------------------- GAT aggregation: wave per node, lane owns 8 channels
// No LDS, no barriers. csr holds srcn directly; 8 lanes of one head redundantly compute identical psum.
__global__ __launch_bounds__(256) void gat_aggregate4(const unsigned short* __restrict__ xtb,
                                                      const float* __restrict__ al_s,
                                                      const float* __restrict__ al_d,
                                                      const int* __restrict__ offsets,
                                                      const int* __restrict__ csr,
                                                      const float* __restrict__ bias,
                                                      unsigned short* __restrict__ outHi,
                                                      unsigned short* __restrict__ outLo) {
    const int lane = threadIdx.x & 63;
    const int n = blockIdx.x * 4 + (threadIdx.x >> 6);
    const int h = lane >> 3;            // head of this lane's channels
    const int c0 = lane * 8;            // channels c0..c0+7
    const int beg = offsets[n];
    const int deg = offsets[n + 1] - beg;
    const float aldv = al_d[n * HEADS + h];

    float acc[8] = {};
    float psum = 0.f;

#pragma unroll 4
    for (int i = 0; i < deg; ++i) {
        int srcn = csr[beg + i];                            // broadcast, src resolved
        float ev = al_s[srcn * HEADS + h] + aldv;
        ev = (ev >= 0.f) ? ev : 0.2f * ev;
        float p = __expf(ev);       // native v_exp; no max-subtraction: ev is O(1), fp32-safe
        psum += p;
        short8 row = *(const short8*)(xtb + (size_t)srcn * HID + c0);
#pragma unroll
        for (int j = 0; j < 8; ++j)
            acc[j] = fmaf(p, bf2f((unsigned short)row[j]), acc[j]);
    }

    const float inv = 1.f / (psum + 1e-16f);
    float4 b0 = *(const float4*)(bias + c0);
    float4 b1 = *(const float4*)(bias + c0 + 4);
    float bv[8] = { b0.x, b0.y, b0.z, b0.w, b1.x, b1.y, b1.z, b1.w };
    short8 h8, l8;
#pragma unroll
    for (int j = 0; j < 8; ++j) {
        float v = acc[j] * inv + bv[j];
        v = (v > 0.f) ? v : expm1f(v);      // ELU
        unsigned short hi = f2bf(v);
        h8[j] = (short)hi;
        l8[j] = (short)f2bf(v - bf2f(hi));
    }
    size_t o = (size_t)n * HID + c0;
    *(short8*)(outHi + o) = h8;
    *(short8*)(outLo + o) = l8;
}

// ---------------------------------------------------------------- pooling
__global__ __launch_bounds__(128) void find_bounds(const int* __restrict__ batch,
                                                   int* __restrict__ bounds) {
    int b = threadIdx.x;
    if (b <= B_GRAPHS) {
        int lo = 0, hi = N_NODES;
        while (lo < hi) {
            int mid = (lo + hi) >> 1;
            if (batch[mid] < b) lo = mid + 1; else hi = mid;
        }
        bounds[b] = lo;
    }
}

// stage A: grid (B_GRAPHS, 8 ch-blocks, 4 node-splits); 8 nodes in flight per block
__global__ __launch_bounds__(256) void pool_partial(const unsigned short* __restrict__ hHi,
                                                    const unsigned short* __restrict__ hLo,
                                                    const int* __restrict__ bounds,
                                                    float* __restrict__ partial) {
    const int b = blockIdx.x, y = blockIdx.y, k = blockIdx.z;
    const int s = bounds[b], cnt = bounds[b + 1] - s;
    const int ns = s + (cnt * k) / 4;
    const int ne = s + (cnt * (k + 1)) / 4;
    const int t = threadIdx.x;
    const int chp = t & 31;            // u32 pair within 64-ch block
    const int nl = t >> 5;             // 0..7

    float a0 = 0.f, a1 = 0.f;
    for (int n = ns + nl; n < ne; n += 8) {
        size_t off = (size_t)n * HID + y * 64 + chp * 2;
        unsigned vh = *(const unsigned*)(hHi + off);
        unsigned vl = *(const unsigned*)(hLo + off);
        a0 += bf2f((unsigned short)(vh & 0xffff)) + bf2f((unsigned short)(vl & 0xffff));
        a1 += bf2f((unsigned short)(vh >> 16)) + bf2f((unsigned short)(vl >> 16));
    }
    __shared__ float red[4][32][2];
    a0 += __shfl_xor(a0, 32);
    a1 += __shfl_xor(a1, 32);
    if ((t & 63) < 32) { red[t >> 6][chp][0] = a0; red[t >> 6][chp][1] = a1; }
    __syncthreads();
    if (t < 64) {
        int cp = t >> 1, c = t & 1;
        float v = red[0][cp][c] + red[1][cp][c] + red[2][cp][c] + red[3][cp][c];
        partial[(((size_t)k * B_GRAPHS + b) * 8 + y) * 64 + cp * 2 + c] = v;
    }
}

// stage B: grid B_GRAPHS x 512 threads
__global__ __launch_bounds__(512) void pool_final(const float* __restrict__ partial,
                                                  const int* __restrict__ bounds,
                                                  float* __restrict__ hG) {
    const int b = blockIdx.x, t = threadIdx.x;
    float v = 0.f;
#pragma unroll
    for (int k = 0; k < 4; ++k)
        v += partial[((size_t)k * B_GRAPHS + b) * HID + t];
    float cnt = fmaxf((float)(bounds[b + 1] - bounds[b]), 1.0f);
    hG[b * HID + t] = v / cnt;
}

// ---------------------------------------------------------------- classifier + softmax
__global__ __launch_bounds__(64) void classifier_kernel(const float* __restrict__ hG,
                                                        const float* __restrict__ Wl,
                                                        const float* __restrict__ bl,
                                                        float* __restrict__ outP) {
    int b = blockIdx.x;
    int tid = threadIdx.x;
    __shared__ float row[HID];
    __shared__ float logit[NCLS];
    for (int j = tid; j < HID; j += 64) row[j] = hG[b * HID + j];
    __syncthreads();
    if (tid < NCLS) {
        float acc = bl[tid];
        for (int j = 0; j < HID; ++j) acc += row[j] * Wl[j * NCLS + tid];
        logit[tid] = acc;
    }
    __syncthreads();
    if (tid == 0) {
        float mx = logit[0];
        for (int k = 1; k < NCLS; ++k) mx = fmaxf(mx, logit[k]);
        float ssum = 0.f, ex[NCLS];
        for (int k = 0; k < NCLS; ++k) { ex[k] = expf(logit[k] - mx); ssum += ex[k]; }
        for (int k = 0; k < NCLS; ++k) outP[b * NCLS + k] = ex[k] / ssum;
    }
}

// ---------------------------------------------------------------- launch
extern "C" void kernel_launch(void* const* d_in, const int* in_sizes, int n_in,
                              void* d_out, int out_size, void* d_ws, size_t ws_size,
                              hipStream_t stream) {
    const float* x     = (const float*)d_in[0];
    const int*   ei    = (const int*)d_in[1];
    const int*   batch = (const int*)d_in[2];
    const float* W[3]  = { (const float*)d_in[3], (const float*)d_in[7],  (const float*)d_in[11] };
    const float* as_[3] = { (const float*)d_in[4], (const float*)d_in[8],  (const float*)d_in[12] };
    const float* ad_[3] = { (const float*)d_in[5], (const float*)d_in[9],  (const float*)d_in[13] };
    const float* bb[3] = { (const float*)d_in[6], (const float*)d_in[10], (const float*)d_in[14] };
    const float* Wl    = (const float*)d_in[15];
    const float* bl    = (const float*)d_in[16];

    // workspace layout
    char* ws = (char*)d_ws;
    unsigned short* A1hi = (unsigned short*)ws;      ws += (size_t)M_PAD * F_INF * 2;  // 10.3 MB
    unsigned short* A1lo = (unsigned short*)ws;      ws += (size_t)M_PAD * F_INF * 2;
    unsigned short* A2hi = (unsigned short*)ws;      ws += (size_t)M_PAD * HID * 2;    // 20.6 MB
    unsigned short* A2lo = (unsigned short*)ws;      ws += (size_t)M_PAD * HID * 2;
    unsigned short* Bthi = (unsigned short*)ws;      ws += (size_t)HID * HID * 2;      // 0.5 MB
    unsigned short* Btlo = (unsigned short*)ws;      ws += (size_t)HID * HID * 2;
    unsigned short* xtb  = (unsigned short*)ws;      ws += (size_t)N_NODES * HID * 2;  // 20.5 MB
    float* als  = (float*)ws;                        ws += (size_t)N_NODES * HEADS * 4;
    float* ald  = (float*)ws;                        ws += (size_t)N_NODES * HEADS * 4;
    float* partial = (float*)ws;                     ws += (size_t)4 * B_GRAPHS * HID * 4; // 512 KB
    int* counts  = (int*)ws;                         ws += (size_t)N_NODES * 4;
    int* incl    = (int*)ws;                         ws += (size_t)N_NODES * 4;
    int* bsum    = (int*)ws;                         ws += 32 * 4;
    int* bpre    = (int*)ws;                         ws += 32 * 4;
    int* offsets = (int*)ws;                         ws += (size_t)(N_NODES + 1) * 4;
    int* cursor  = (int*)ws;                         ws += (size_t)N_NODES * 4;
    int* csr     = (int*)ws;                         ws += (size_t)E_TOT * 4;
    int* bounds  = (int*)ws;                         ws += (size_t)(B_GRAPHS + 1) * 4;

    float* hG = (float*)d_out;                 // 64*512
    float* probs = (float*)d_out + (size_t)B_GRAPHS * HID;

    // ---- CSR build (identical every call; rebuilt for determinism/no-caching)
    zero_ints<<<(N_NODES + 255) / 256, 256, 0, stream>>>(counts, N_NODES);
    count_edges<<<(E_TOT + 255) / 256, 256, 0, stream>>>(ei, counts);
    scan_local<<<NSCAN, 1024, 0, stream>>>(counts, incl, bsum);
    scan_bsums<<<1, 64, 0, stream>>>(bsum, bpre);
    scan_finalize<<<NSCAN, 1024, 0, stream>>>(counts, incl, bpre, offsets, cursor);
    scatter_edges<<<(E_TOT + 255) / 256, 256, 0, stream>>>(ei, cursor, csr);
    find_bounds<<<1, 128, 0, stream>>>(batch, bounds);
    zero_pad_rows<<<((M_PAD - N_NODES) * HID + 255) / 256, 256, 0, stream>>>(A2hi, A2lo);

    // ---- layer 1 (K = 256)
    {
        long totA = (long)M_PAD * F_INF;
        split_pad<<<(int)(totA / 4 / 256), 256, 0, stream>>>(x, A1hi, A1lo, N_NODES, F_INF, totA);
        transpose_split_B<<<dim3(HID / 32, F_INF / 32), 256, 0, stream>>>(W[0], Bthi, Btlo, F_INF);
        gemm_mfma<<<NWG_GEMM, 256, 0, stream>>>(A1hi, A1lo, Bthi, Btlo, as_[0], ad_[0],
                                                xtb, als, ald, N_NODES, F_INF);
        gat_aggregate4<<<N_NODES / 4, 256, 0, stream>>>(xtb, als, ald, offsets, csr, bb[0], A2hi, A2lo);
    }

    // ---- layers 2,3 (K = 512)
    for (int L = 1; L < 3; ++L) {
        transpose_split_B<<<dim3(HID / 32, HID / 32), 256, 0, stream>>>(W[L], Bthi, Btlo, HID);
        gemm_mfma<<<NWG_GEMM, 256, 0, stream>>>(A2hi, A2lo, Bthi, Btlo, as_[L], ad_[L],
                                                xtb, als, ald, N_NODES, HID);
        gat_aggregate4<<<N_NODES / 4, 256, 0, stream>>>(xtb, als, ald, offsets, csr, bb[L], A2hi, A2lo);
    }

    // ---- pool + classify
    {
        dim3 pgrid(B_GRAPHS, 8, 4);
        pool_partial<<<pgrid, 256, 0, stream>>>(A2hi, A2lo, bounds, partial);
        pool_final<<<B_GRAPHS, 512, 0, stream>>>(partial, bounds, hG);
    }
    classifier_kernel<<<B_GRAPHS, 64, 0, stream>>>(hG, Wl, bl, probs);
}

// Round 10
// 384.035 us; speedup vs baseline: 2.4397x; 1.0554x over previous
//
#include <hip/hip_runtime.h>
#include <hip/hip_bf16.h>
#include <math.h>

#define N_NODES  20000
#define E_EDGES  320000
#define E_TOT    (E_EDGES + N_NODES)
#define F_INF    256
#define HEADS    8
#define CDIM     64
#define HID      512
#define B_GRAPHS 64
#define NCLS     10
#define M_PAD    20096          // 157 * 128
#define NSCAN    20             // ceil(20000/1024)
#define NWG_GEMM 1256           // 157 row-panels * 8 col-tiles (64 wide)

typedef __attribute__((ext_vector_type(8))) short short8;
typedef __attribute__((ext_vector_type(4))) float f32x4;

__device__ inline unsigned short f2bf(float x) {
    unsigned u = __builtin_bit_cast(unsigned, x);
    u += 0x7fff + ((u >> 16) & 1);          // round-to-nearest-even
    return (unsigned short)(u >> 16);
}
__device__ inline float bf2f(unsigned short h) {
    unsigned u = ((unsigned)h) << 16;
    return __builtin_bit_cast(float, u);
}

#define GLOAD_LDS16(g, l) __builtin_amdgcn_global_load_lds(                     \
        (const __attribute__((address_space(1))) void*)(g),                     \
        (__attribute__((address_space(3))) void*)(l), 16, 0, 0)

// ---------------------------------------------------------------- utils
__global__ __launch_bounds__(256) void zero_ints(int* p, int n) {
    int i = blockIdx.x * 256 + threadIdx.x;
    if (i < n) p[i] = 0;
}

__global__ __launch_bounds__(256) void zero_pad_rows(unsigned short* hi, unsigned short* lo) {
    int i = blockIdx.x * 256 + threadIdx.x;
    const int tot = (M_PAD - N_NODES) * HID;
    if (i < tot) {
        hi[(size_t)N_NODES * HID + i] = 0;
        lo[(size_t)N_NODES * HID + i] = 0;
    }
}

// ---------------------------------------------------------------- fp32 -> bf16 hi/lo split (row-padded)
__global__ __launch_bounds__(256) void split_pad(const float* __restrict__ src,
                                                 unsigned short* __restrict__ hi,
                                                 unsigned short* __restrict__ lo,
                                                 int M, int K, long total) {
    long i = ((long)blockIdx.x * 256 + threadIdx.x) * 4;
    if (i >= total) return;
    int row = (int)(i / K);
    float4 v = make_float4(0.f, 0.f, 0.f, 0.f);
    if (row < M) v = *(const float4*)(src + i);
    ushort4 h, l;
    h.x = f2bf(v.x); l.x = f2bf(v.x - bf2f(h.x));
    h.y = f2bf(v.y); l.y = f2bf(v.y - bf2f(h.y));
    h.z = f2bf(v.z); l.z = f2bf(v.z - bf2f(h.z));
    h.w = f2bf(v.w); l.w = f2bf(v.w - bf2f(h.w));
    *(ushort4*)(hi + i) = h;
    *(ushort4*)(lo + i) = l;
}

// ---------------------------------------------------------------- B[K][512] -> Bt_hi/lo[512][K]
__global__ __launch_bounds__(256) void transpose_split_B(const float* __restrict__ B,
                                                         unsigned short* __restrict__ Bthi,
                                                         unsigned short* __restrict__ Btlo,
                                                         int K) {
    __shared__ float t[32][33];
    int n0 = blockIdx.x * 32, k0 = blockIdx.y * 32;
    int tx = threadIdx.x & 31, ty = threadIdx.x >> 5;     // 32 x 8
    for (int i = ty; i < 32; i += 8) t[i][tx] = B[(size_t)(k0 + i) * HID + n0 + tx];
    __syncthreads();
    for (int i = ty; i < 32; i += 8) {
        float v = t[tx][i];                                // = B[k0+tx][n0+i]
        unsigned short h = f2bf(v);
        unsigned short l = f2bf(v - bf2f(h));
        Bthi[(size_t)(n0 + i) * K + k0 + tx] = h;
        Btlo[(size_t)(n0 + i) * K + k0 + tx] = l;
    }
}

// ---------------------------------------------------------------- bf16x3 MFMA GEMM, 128x64 tile (occupancy-sized):
// grid = 1256 = 4.9 blocks/CU; 24KB LDS single buffer -> 4-5 resident blocks/CU hide the barrier drain (m97/m114).
// Wave w owns rows [w*32, w*32+32) x all 64 cols (= one head) -> fused al epilogue unchanged.
// LDS 16B-unit u: (row=u>>2, kgrp=(u&3)^((row>>1)&3)) -> 2-way-max bank aliasing on ds_read_b128.
__global__ __launch_bounds__(256) void gemm_mfma(const unsigned short* __restrict__ Ahi,
                                                 const unsigned short* __restrict__ Alo,
                                                 const unsigned short* __restrict__ Bhi,
                                                 const unsigned short* __restrict__ Blo,
                                                 const float* __restrict__ a_src,
                                                 const float* __restrict__ a_dst,
                                                 unsigned short* __restrict__ xtb,
                                                 float* __restrict__ al_s,
                                                 float* __restrict__ al_d,
                                                 int M, int K) {
    __shared__ short AsHi[4096], AsLo[4096], BsHi[2048], BsLo[2048];   // 24 KB
    const int tid = threadIdx.x;
    const int w = tid >> 6, lane = tid & 63;

    // bijective XCD-chunked swizzle: nwg=1256, q=157, r=0 -> wg = xcd*157 + idx
    const int xcd = blockIdx.x & 7, idx = blockIdx.x >> 3;
    const int wg = xcd * (NWG_GEMM >> 3) + idx;
    const int row0 = (wg >> 3) * 128, col0 = (wg & 7) * 64;

    // staging: A units 0..511 (4/row), wave w covers [w*128, w*128+128) via 2 instrs;
    //          B units 0..255 (4/row), wave w covers [w*64, w*64+64) via 1 instr.
    long offA[2];
    int ldsA[2];
#pragma unroll
    for (int i = 0; i < 2; ++i) {
        int u = w * 128 + i * 64 + lane;
        int row = u >> 2;
        int kg = (u & 3) ^ ((row >> 1) & 3);               // inverse of read swizzle
        offA[i] = ((long)(row0 + row) * K + kg * 8) * 2;   // bytes
        ldsA[i] = (w * 128 + i * 64) * 8;                  // short index
    }
    long offB;
    int ldsB;
    {
        int u = w * 64 + lane;
        int row = u >> 2;
        int kg = (u & 3) ^ ((row >> 1) & 3);
        offB = ((long)(col0 + row) * K + kg * 8) * 2;
        ldsB = (w * 64) * 8;
    }

    const int r16 = lane & 15, kg = lane >> 4;
    int aOff[2], bOff[4];
#pragma unroll
    for (int i = 0; i < 2; ++i) {
        int row = w * 32 + i * 16 + r16;
        aOff[i] = (row * 4 + (kg ^ ((row >> 1) & 3))) * 16;
    }
#pragma unroll
    for (int j = 0; j < 4; ++j) {
        int col = j * 16 + r16;
        bOff[j] = (col * 4 + (kg ^ ((col >> 1) & 3))) * 16;
    }

    const char* pAhi = (const char*)Ahi;
    const char* pAlo = (const char*)Alo;
    const char* pBhi = (const char*)Bhi;
    const char* pBlo = (const char*)Blo;

    f32x4 acc[2][4] = {};

    for (int kk = 0; kk < K; kk += 32) {
        long kb = (long)kk * 2;
        __syncthreads();                 // previous step's ds_reads done
#pragma unroll
        for (int i = 0; i < 2; ++i) {
            GLOAD_LDS16(pAhi + offA[i] + kb, AsHi + ldsA[i]);
            GLOAD_LDS16(pAlo + offA[i] + kb, AsLo + ldsA[i]);
        }
        GLOAD_LDS16(pBhi + offB + kb, BsHi + ldsB);
        GLOAD_LDS16(pBlo + offB + kb, BsLo + ldsB);
        __syncthreads();                 // drains vmcnt; other resident blocks run through this

        short8 fah[2], fal[2], fbh[4], fbl[4];
#pragma unroll
        for (int i = 0; i < 2; ++i) {
            fah[i] = *(const short8*)((const char*)AsHi + aOff[i]);
            fal[i] = *(const short8*)((const char*)AsLo + aOff[i]);
        }
#pragma unroll
        for (int j = 0; j < 4; ++j) {
            fbh[j] = *(const short8*)((const char*)BsHi + bOff[j]);
            fbl[j] = *(const short8*)((const char*)BsLo + bOff[j]);
        }
#pragma unroll
        for (int i = 0; i < 2; ++i)
#pragma unroll
            for (int j = 0; j < 4; ++j) {
                acc[i][j] = __builtin_amdgcn_mfma_f32_16x16x32_bf16(fah[i], fbh[j], acc[i][j], 0, 0, 0);
                acc[i][j] = __builtin_amdgcn_mfma_f32_16x16x32_bf16(fah[i], fbl[j], acc[i][j], 0, 0, 0);
                acc[i][j] = __builtin_amdgcn_mfma_f32_16x16x32_bf16(fal[i], fbh[j], acc[i][j], 0, 0, 0);
            }
    }

    // ---- epilogue. C/D layout: col=lane&15 within 16-block, row=(lane>>4)*4+rr.
    // This block's 64 cols = head h; every wave spans all 4 j-blocks of that head.
    const int h = col0 >> 6;
    float asv[4], adv[4];
#pragma unroll
    for (int j = 0; j < 4; ++j) {
        asv[j] = a_src[h * CDIM + j * 16 + r16];
        adv[j] = a_dst[h * CDIM + j * 16 + r16];
    }
#pragma unroll
    for (int i = 0; i < 2; ++i) {
        int rbase = row0 + w * 32 + i * 16 + (lane >> 4) * 4;
        // al_s / al_d: dot over the 64 channels of head h (4 j-blocks x 16 lanes)
#pragma unroll
        for (int rr = 0; rr < 4; ++rr) {
            float ss = acc[i][0][rr] * asv[0] + acc[i][1][rr] * asv[1]
                     + acc[i][2][rr] * asv[2] + acc[i][3][rr] * asv[3];
            float dd = acc[i][0][rr] * adv[0] + acc[i][1][rr] * adv[1]
                     + acc[i][2][rr] * adv[2] + acc[i][3][rr] * adv[3];
#pragma unroll
            for (int off = 1; off < 16; off <<= 1) {
                ss += __shfl_xor(ss, off);
                dd += __shfl_xor(dd, off);
            }
            int row = rbase + rr;
            if ((lane & 15) == 0 && row < M) {
                al_s[row * HEADS + h] = ss;
                al_d[row * HEADS + h] = dd;
            }
        }
        // xtb bf16 store
#pragma unroll
        for (int j = 0; j < 4; ++j) {
            int col = col0 + j * 16 + r16;
#pragma unroll
            for (int rr = 0; rr < 4; ++rr)
                if (rbase + rr < M) xtb[(size_t)(rbase + rr) * HID + col] = f2bf(acc[i][j][rr]);
        }
    }
}

// ---------------------------------------------------------------- CSR build
__global__ __launch_bounds__(256) void count_edges(const int* __restrict__ ei,
                                                   int* __restrict__ counts) {
    int e = blockIdx.x * 256 + threadIdx.x;
    if (e < E_TOT) {
        int dst = (e < E_EDGES) ? ei[E_EDGES + e] : (e - E_EDGES);
        atomicAdd(&counts[dst], 1);
    }
}

// parallel 3-phase scan
__global__ __launch_bounds__(1024) void scan_local(const int* __restrict__ counts,
                                                   int* __restrict__ incl,
                                                   int* __restrict__ bsum) {
    __shared__ int s[1024];
    int tid = threadIdx.x;
    int i = blockIdx.x * 1024 + tid;
    int v = (i < N_NODES) ? counts[i] : 0;
    s[tid] = v;
    __syncthreads();
    for (int off = 1; off < 1024; off <<= 1) {
        int t = (tid >= off) ? s[tid - off] : 0;
        __syncthreads();
        s[tid] += t;
        __syncthreads();
    }
    if (i < N_NODES) incl[i] = s[tid];
    if (tid == 1023) bsum[blockIdx.x] = s[1023];
}

__global__ __launch_bounds__(64) void scan_bsums(const int* __restrict__ bsum,
                                                 int* __restrict__ bpre) {
    int lane = threadIdx.x;
    int v = (lane < NSCAN) ? bsum[lane] : 0;
    int incl = v;
#pragma unroll
    for (int off = 1; off < 32; off <<= 1) {
        int t = __shfl_up(incl, off);
        if (lane >= off) incl += t;
    }
    if (lane < NSCAN) bpre[lane] = incl - v;
}

__global__ __launch_bounds__(1024) void scan_finalize(const int* __restrict__ counts,
                                                      const int* __restrict__ incl,
                                                      const int* __restrict__ bpre,
                                                      int* __restrict__ offsets,
                                                      int* __restrict__ cursor) {
    int i = blockIdx.x * 1024 + threadIdx.x;
    if (i < N_NODES) {
        int inc = incl[i] + bpre[blockIdx.x];
        offsets[i + 1] = inc;
        cursor[i] = inc - counts[i];
    }
    if (i == 0) offsets[0] = 0;
}

// stores srcn DIRECTLY (self-loop: srcn = dst) -> aggregation needs no ei load, no branch
__global__ __launch_bounds__(256) void scatter_edges(const int* __restrict__ ei,
                                                     int* __restrict__ cursor,
                                                     int* __restrict__ csr) {
    int e = blockIdx.x * 256 + threadIdx.x;
    if (e < E_TOT) {
        int srcn, dst;
        if (e < E_EDGES) { srcn = ei[e]; dst = ei[E_EDGES + e]; }
        else             { srcn = dst = e - E_EDGES; }
        int pos = atomicAdd(&cursor[dst], 1);
        csr[pos] = srcn;
    }
}

// ---------------------------------------------------------------- GAT aggregation: wave per node, lane owns 8 channels
// No LDS, no barriers. csr holds srcn directly; 8 lanes of one head redundantly compute identical psum.
__global__ __launch_bounds__(256) void gat_aggregate4(const unsigned short* __restrict__ xtb,
                                                      const float* __restrict__ al_s,
                                                      const float* __restrict__ al_d,
                                                      const int* __restrict__ offsets,
                                                      const int* __restrict__ csr,
                                                      const float* __restrict__ bias,
                                                      unsigned short* __restrict__ outHi,
                                                      unsigned short* __restrict__ outLo) {
    const int lane = threadIdx.x & 63;
    const int n = blockIdx.x * 4 + (threadIdx.x >> 6);
    const int h = lane >> 3;            // head of this lane's channels
    const int c0 = lane * 8;            // channels c0..c0+7
    const int beg = offsets[n];
    const int deg = offsets[n + 1] - beg;
    const float aldv = al_d[n * HEADS + h];

    float acc[8] = {};
    float psum = 0.f;

#pragma unroll 4
    for (int i = 0; i < deg; ++i) {
        int srcn = csr[beg + i];                            // broadcast, src resolved
        float ev = al_s[srcn * HEADS + h] + aldv;
        ev = (ev >= 0.f) ? ev : 0.2f * ev;
        float p = __expf(ev);       // native v_exp; no max-subtraction: ev is O(1), fp32-safe
        psum += p;
        short8 row = *(const short8*)(xtb + (size_t)srcn * HID + c0);
#pragma unroll
        for (int j = 0; j < 8; ++j)
            acc[j] = fmaf(p, bf2f((unsigned short)row[j]), acc[j]);
    }

    const float inv = 1.f / (psum + 1e-16f);
    float4 b0 = *(const float4*)(bias + c0);
    float4 b1 = *(const float4*)(bias + c0 + 4);
    float bv[8] = { b0.x, b0.y, b0.z, b0.w, b1.x, b1.y, b1.z, b1.w };
    short8 h8, l8;
#pragma unroll
    for (int j = 0; j < 8; ++j) {
        float v = acc[j] * inv + bv[j];
        v = (v > 0.f) ? v : expm1f(v);      // ELU
        unsigned short hi = f2bf(v);
        h8[j] = (short)hi;
        l8[j] = (short)f2bf(v - bf2f(hi));
    }
    size_t o = (size_t)n * HID + c0;
    *(short8*)(outHi + o) = h8;
    *(short8*)(outLo + o) = l8;
}

// ---------------------------------------------------------------- pooling
__global__ __launch_bounds__(128) void find_bounds(const int* __restrict__ batch,
                                                   int* __restrict__ bounds) {
    int b = threadIdx.x;
    if (b <= B_GRAPHS) {
        int lo = 0, hi = N_NODES;
        while (lo < hi) {
            int mid = (lo + hi) >> 1;
            if (batch[mid] < b) lo = mid + 1; else hi = mid;
        }
        bounds[b] = lo;
    }
}

// stage A: grid (B_GRAPHS, 8 ch-blocks, 4 node-splits); 8 nodes in flight per block
__global__ __launch_bounds__(256) void pool_partial(const unsigned short* __restrict__ hHi,
                                                    const unsigned short* __restrict__ hLo,
                                                    const int* __restrict__ bounds,
                                                    float* __restrict__ partial) {
    const int b = blockIdx.x, y = blockIdx.y, k = blockIdx.z;
    const int s = bounds[b], cnt = bounds[b + 1] - s;
    const int ns = s + (cnt * k) / 4;
    const int ne = s + (cnt * (k + 1)) / 4;
    const int t = threadIdx.x;
    const int chp = t & 31;            // u32 pair within 64-ch block
    const int nl = t >> 5;             // 0..7

    float a0 = 0.f, a1 = 0.f;
    for (int n = ns + nl; n < ne; n += 8) {
        size_t off = (size_t)n * HID + y * 64 + chp * 2;
        unsigned vh = *(const unsigned*)(hHi + off);
        unsigned vl = *(const unsigned*)(hLo + off);
        a0 += bf2f((unsigned short)(vh & 0xffff)) + bf2f((unsigned short)(vl & 0xffff));
        a1 += bf2f((unsigned short)(vh >> 16)) + bf2f((unsigned short)(vl >> 16));
    }
    __shared__ float red[4][32][2];
    a0 += __shfl_xor(a0, 32);
    a1 += __shfl_xor(a1, 32);
    if ((t & 63) < 32) { red[t >> 6][chp][0] = a0; red[t >> 6][chp][1] = a1; }
    __syncthreads();
    if (t < 64) {
        int cp = t >> 1, c = t & 1;
        float v = red[0][cp][c] + red[1][cp][c] + red[2][cp][c] + red[3][cp][c];
        partial[(((size_t)k * B_GRAPHS + b) * 8 + y) * 64 + cp * 2 + c] = v;
    }
}

// stage B: grid B_GRAPHS x 512 threads
__global__ __launch_bounds__(512) void pool_final(const float* __restrict__ partial,
                                                  const int* __restrict__ bounds,
                                                  float* __restrict__ hG) {
    const int b = blockIdx.x, t = threadIdx.x;
    float v = 0.f;
#pragma unroll
    for (int k = 0; k < 4; ++k)
        v += partial[((size_t)k * B_GRAPHS + b) * HID + t];
    float cnt = fmaxf((float)(bounds[b + 1] - bounds[b]), 1.0f);
    hG[b * HID + t] = v / cnt;
}

// ---------------------------------------------------------------- classifier + softmax
__global__ __launch_bounds__(64) void classifier_kernel(const float* __restrict__ hG,
                                                        const float* __restrict__ Wl,
                                                        const float* __restrict__ bl,
                                                        float* __restrict__ outP) {
    int b = blockIdx.x;
    int tid = threadIdx.x;
    __shared__ float row[HID];
    __shared__ float logit[NCLS];
    for (int j = tid; j < HID; j += 64) row[j] = hG[b * HID + j];
    __syncthreads();
    if (tid < NCLS) {
        float acc = bl[tid];
        for (int j = 0; j < HID; ++j) acc += row[j] * Wl[j * NCLS + tid];
        logit[tid] = acc;
    }
    __syncthreads();
    if (tid == 0) {
        float mx = logit[0];
        for (int k = 1; k < NCLS; ++k) mx = fmaxf(mx, logit[k]);
        float ssum = 0.f, ex[NCLS];
        for (int k = 0; k < NCLS; ++k) { ex[k] = expf(logit[k] - mx); ssum += ex[k]; }
        for (int k = 0; k < NCLS; ++k) outP[b * NCLS + k] = ex[k] / ssum;
    }
}

// ---------------------------------------------------------------- launch
extern "C" void kernel_launch(void* const* d_in, const int* in_sizes, int n_in,
                              void* d_out, int out_size, void* d_ws, size_t ws_size,
                              hipStream_t stream) {
    const float* x     = (const float*)d_in[0];
    const int*   ei    = (const int*)d_in[1];
    const int*   batch = (const int*)d_in[2];
    const float* W[3]  = { (const float*)d_in[3], (const float*)d_in[7],  (const float*)d_in[11] };
    const float* as_[3] = { (const float*)d_in[4], (const float*)d_in[8],  (const float*)d_in[12] };
    const float* ad_[3] = { (const float*)d_in[5], (const float*)d_in[9],  (const float*)d_in[13] };
    const float* bb[3] = { (const float*)d_in[6], (const float*)d_in[10], (const float*)d_in[14] };
    const float* Wl    = (const float*)d_in[15];
    const float* bl    = (const float*)d_in[16];

    // workspace layout
    char* ws = (char*)d_ws;
    unsigned short* A1hi = (unsigned short*)ws;      ws += (size_t)M_PAD * F_INF * 2;  // 10.3 MB
    unsigned short* A1lo = (unsigned short*)ws;      ws += (size_t)M_PAD * F_INF * 2;
    unsigned short* A2hi = (unsigned short*)ws;      ws += (size_t)M_PAD * HID * 2;    // 20.6 MB
    unsigned short* A2lo = (unsigned short*)ws;      ws += (size_t)M_PAD * HID * 2;
    unsigned short* Bthi = (unsigned short*)ws;      ws += (size_t)HID * HID * 2;      // 0.5 MB
    unsigned short* Btlo = (unsigned short*)ws;      ws += (size_t)HID * HID * 2;
    unsigned short* xtb  = (unsigned short*)ws;      ws += (size_t)N_NODES * HID * 2;  // 20.5 MB
    float* als  = (float*)ws;                        ws += (size_t)N_NODES * HEADS * 4;
    float* ald  = (float*)ws;                        ws += (size_t)N_NODES * HEADS * 4;
    float* partial = (float*)ws;                     ws += (size_t)4 * B_GRAPHS * HID * 4; // 512 KB
    int* counts  = (int*)ws;                         ws += (size_t)N_NODES * 4;
    int* incl    = (int*)ws;                         ws += (size_t)N_NODES * 4;
    int* bsum    = (int*)ws;                         ws += 32 * 4;
    int* bpre    = (int*)ws;                         ws += 32 * 4;
    int* offsets = (int*)ws;                         ws += (size_t)(N_NODES + 1) * 4;
    int* cursor  = (int*)ws;                         ws += (size_t)N_NODES * 4;
    int* csr     = (int*)ws;                         ws += (size_t)E_TOT * 4;
    int* bounds  = (int*)ws;                         ws += (size_t)(B_GRAPHS + 1) * 4;

    float* hG = (float*)d_out;                 // 64*512
    float* probs = (float*)d_out + (size_t)B_GRAPHS * HID;

    // ---- CSR build (identical every call; rebuilt for determinism/no-caching)
    zero_ints<<<(N_NODES + 255) / 256, 256, 0, stream>>>(counts, N_NODES);
    count_edges<<<(E_TOT + 255) / 256, 256, 0, stream>>>(ei, counts);
    scan_local<<<NSCAN, 1024, 0, stream>>>(counts, incl, bsum);
    scan_bsums<<<1, 64, 0, stream>>>(bsum, bpre);
    scan_finalize<<<NSCAN, 1024, 0, stream>>>(counts, incl, bpre, offsets, cursor);
    scatter_edges<<<(E_TOT + 255) / 256, 256, 0, stream>>>(ei, cursor, csr);
    find_bounds<<<1, 128, 0, stream>>>(batch, bounds);
    zero_pad_rows<<<((M_PAD - N_NODES) * HID + 255) / 256, 256, 0, stream>>>(A2hi, A2lo);

    // ---- layer 1 (K = 256)
    {
        long totA = (long)M_PAD * F_INF;
        split_pad<<<(int)(totA / 4 / 256), 256, 0, stream>>>(x, A1hi, A1lo, N_NODES, F_INF, totA);
        transpose_split_B<<<dim3(HID / 32, F_INF / 32), 256, 0, stream>>>(W[0], Bthi, Btlo, F_INF);
        gemm_mfma<<<NWG_GEMM, 256, 0, stream>>>(A1hi, A1lo, Bthi, Btlo, as_[0], ad_[0],
                                                xtb, als, ald, N_NODES, F_INF);
        gat_aggregate4<<<N_NODES / 4, 256, 0, stream>>>(xtb, als, ald, offsets, csr, bb[0], A2hi, A2lo);
    }

    // ---- layers 2,3 (K = 512)
    for (int L = 1; L < 3; ++L) {
        transpose_split_B<<<dim3(HID / 32, HID / 32), 256, 0, stream>>>(W[L], Bthi, Btlo, HID);
        gemm_mfma<<<NWG_GEMM, 256, 0, stream>>>(A2hi, A2lo, Bthi, Btlo, as_[L], ad_[L],
                                                xtb, als, ald, N_NODES, HID);
        gat_aggregate4<<<N_NODES / 4, 256, 0, stream>>>(xtb, als, ald, offsets, csr, bb[L], A2hi, A2lo);
    }

    // ---- pool + classify
    {
        dim3 pgrid(B_GRAPHS, 8, 4);
        pool_partial<<<pgrid, 256, 0, stream>>>(A2hi, A2lo, bounds, partial);
        pool_final<<<B_GRAPHS, 512, 0, stream>>>(partial, bounds, hG);
    }
    classifier_kernel<<<B_GRAPHS, 64, 0, stream>>>(hG, Wl, bl, probs);
}